// Round 1
// baseline (1404.586 us; speedup 1.0000x reference)
//
#include <hip/hip_runtime.h>
#include <hip/hip_bf16.h>
#include <math.h>

typedef __attribute__((ext_vector_type(8))) short bf16x8;
typedef __attribute__((ext_vector_type(4))) float f32x4;
typedef __attribute__((ext_vector_type(8))) unsigned short u16x8;
typedef __attribute__((ext_vector_type(4))) unsigned short u16x4;

static constexpr int B = 4, S = 2048, D = 2048, H = 16, DH = 128;
static constexpr int N3 = 3 * D;   // 6144
static constexpr int M = B * S;    // 8192

__device__ __forceinline__ unsigned short f2bf(float f) {
  unsigned u = __float_as_uint(f);
  u += 0x7fffu + ((u >> 16) & 1u);
  return (unsigned short)(u >> 16);
}
__device__ __forceinline__ float bf2f(unsigned short b) {
  return __uint_as_float(((unsigned)b) << 16);
}

// ---------------- elementwise f32 -> bf16 convert (vectorized) ----------------
__global__ __launch_bounds__(256) void cvt_kernel(const float* __restrict__ in,
                                                  unsigned short* __restrict__ out) {
  size_t i = (size_t)blockIdx.x * 256 + threadIdx.x;
  f32x4 v = *(const f32x4*)(in + i * 4);
  u16x4 o;
  o[0] = f2bf(v[0]); o[1] = f2bf(v[1]); o[2] = f2bf(v[2]); o[3] = f2bf(v[3]);
  *(u16x4*)(out + i * 4) = o;
}

// ---------------- tiled transpose-convert: W (K,N) f32 -> WT (N,K) bf16 ----------------
__global__ __launch_bounds__(256) void transpose_kernel(const float* __restrict__ W,
                                                        unsigned short* __restrict__ WT,
                                                        int K, int N) {
  __shared__ float t[32][33];
  int tx = threadIdx.x, ty = threadIdx.y;
  int n0 = blockIdx.x * 32, k0 = blockIdx.y * 32;
#pragma unroll
  for (int i = 0; i < 4; i++)
    t[ty + i * 8][tx] = W[(size_t)(k0 + ty + i * 8) * N + n0 + tx];
  __syncthreads();
#pragma unroll
  for (int i = 0; i < 4; i++)
    WT[(size_t)(n0 + ty + i * 8) * K + k0 + tx] = f2bf(t[tx][ty + i * 8]);
}

// ---------------- async global->LDS helper ----------------
__device__ __forceinline__ void gload_lds(const void* g, void* l) {
  __builtin_amdgcn_global_load_lds((const __attribute__((address_space(1))) void*)g,
                                   (__attribute__((address_space(3))) void*)l, 16, 0, 0);
}

// ---------------- bf16 MFMA GEMM: C = A(M,K) * Bt(N,K)^T + bias ----------------
// EPI 0: scatter epilogue -> Q (b,h,s,d), K (b,h,s,d), VT (b,h,d,s), all bf16
// EPI 1: plain f32 store to Cf (M,N)
template <int EPI>
__global__ __launch_bounds__(256) void gemm_bt(
    const unsigned short* __restrict__ A, const unsigned short* __restrict__ Bt,
    const float* __restrict__ bias, float* __restrict__ Cf,
    unsigned short* __restrict__ Qp, unsigned short* __restrict__ Kp,
    unsigned short* __restrict__ VTp, int Nn, int Kk) {
  __shared__ __align__(16) unsigned short lA[128 * 32];
  __shared__ __align__(16) unsigned short lB[128 * 32];
  const int tid = threadIdx.x;
  const int l = tid & 63;
  const int w = tid >> 6;
  const int lr = l >> 4, lc = l & 15;
  const int wr = w >> 1, wc = w & 1;
  const int bm = blockIdx.x, bn = blockIdx.y;

  f32x4 acc[4][4];
#pragma unroll
  for (int m = 0; m < 4; m++)
#pragma unroll
    for (int n = 0; n < 4; n++) acc[m][n] = (f32x4)0.f;

  const int srow = tid >> 2;        // 0..63
  const int sk = (tid & 3) * 8;     // 0,8,16,24
  const unsigned short* Ab = A + (size_t)(bm * 128 + srow) * Kk + sk;
  const unsigned short* Bb = Bt + (size_t)(bn * 128 + srow) * Kk + sk;
  unsigned short* lA0 = lA + (size_t)tid * 8;
  unsigned short* lB0 = lB + (size_t)tid * 8;

  for (int kt = 0; kt < Kk; kt += 32) {
    __syncthreads();
    gload_lds(Ab + kt, lA0);
    gload_lds(Ab + (size_t)64 * Kk + kt, lA0 + 256 * 8);
    gload_lds(Bb + kt, lB0);
    gload_lds(Bb + (size_t)64 * Kk + kt, lB0 + 256 * 8);
    __syncthreads();
    bf16x8 af[4], bfr[4];
#pragma unroll
    for (int m = 0; m < 4; m++)
      af[m] = *(const bf16x8*)(lA + (wr * 64 + m * 16 + lc) * 32 + lr * 8);
#pragma unroll
    for (int n = 0; n < 4; n++)
      bfr[n] = *(const bf16x8*)(lB + (wc * 64 + n * 16 + lc) * 32 + lr * 8);
#pragma unroll
    for (int m = 0; m < 4; m++)
#pragma unroll
      for (int n = 0; n < 4; n++)
        acc[m][n] = __builtin_amdgcn_mfma_f32_16x16x32_bf16(af[m], bfr[n], acc[m][n], 0, 0, 0);
  }

#pragma unroll
  for (int m = 0; m < 4; m++) {
#pragma unroll
    for (int n = 0; n < 4; n++) {
      const int col = bn * 128 + wc * 64 + n * 16 + lc;
      const float bv = bias[col];
#pragma unroll
      for (int r = 0; r < 4; r++) {
        const int row = bm * 128 + wr * 64 + m * 16 + lr * 4 + r;
        const float v = acc[m][n][r] + bv;
        if (EPI == 0) {
          const unsigned short ob = f2bf(v);
          const int b = row >> 11, s = row & 2047;
          const int which = col >> 11, within = col & 2047;
          const int h = within >> 7, d = within & 127;
          const size_t bh = (size_t)(b * H + h);
          if (which == 0)      Qp[(bh * S + s) * DH + d] = ob;
          else if (which == 1) Kp[(bh * S + s) * DH + d] = ob;
          else                 VTp[(bh * DH + d) * S + s] = ob;
        } else {
          Cf[(size_t)row * Nn + col] = v;
        }
      }
    }
  }
}

// ---------------- RoPE in-place on (BH, S, DH) bf16, interleaved pairs ----------------
__global__ __launch_bounds__(256) void rope_kernel(unsigned short* __restrict__ T,
                                                   const float* __restrict__ cosT,
                                                   const float* __restrict__ sinT) {
  int t = blockIdx.x * 256 + threadIdx.x;
  int d8 = t & 15;
  int s = (t >> 4) & (S - 1);
  size_t off = (size_t)t * 8;
  u16x8 v = *(const u16x8*)(T + off);
  f32x4 c = *(const f32x4*)(cosT + (size_t)s * (DH / 2) + d8 * 4);
  f32x4 sn = *(const f32x4*)(sinT + (size_t)s * (DH / 2) + d8 * 4);
  u16x8 o;
#pragma unroll
  for (int j = 0; j < 4; j++) {
    float x1 = bf2f(v[2 * j]), x2 = bf2f(v[2 * j + 1]);
    o[2 * j]     = f2bf(x1 * c[j] - x2 * sn[j]);
    o[2 * j + 1] = f2bf(x1 * sn[j] + x2 * c[j]);
  }
  *(u16x8*)(T + off) = o;
}

// ---------------- flash attention: 1 wave per 16 q-rows, KV tiles of 32 ----------------
__global__ __launch_bounds__(256) void attn_kernel(const unsigned short* __restrict__ Q,
                                                   const unsigned short* __restrict__ Kt,
                                                   const unsigned short* __restrict__ VT,
                                                   unsigned short* __restrict__ O) {
  __shared__ __align__(16) unsigned short lP[4][16 * 32];
  const int tid = threadIdx.x;
  const int w = tid >> 6, l = tid & 63;
  const int lr = l >> 4, lc = l & 15;
  const int bh = blockIdx.x >> 5;     // S/64 = 32 q-groups per head
  const int qg = blockIdx.x & 31;
  const int qr0 = qg * 64 + w * 16;
  const int b = bh >> 4, h = bh & 15;
  const size_t base = (size_t)bh * S * DH;
  const float scale = 0.088388347648318447f;  // 1/sqrt(128)

  bf16x8 aq[4];
#pragma unroll
  for (int t = 0; t < 4; t++)
    aq[t] = *(const bf16x8*)(Q + base + (size_t)(qr0 + lc) * DH + t * 32 + lr * 8);

  f32x4 acc[8];
#pragma unroll
  for (int dt = 0; dt < 8; dt++) acc[dt] = (f32x4)0.f;
  float mrow[4] = {-INFINITY, -INFINITY, -INFINITY, -INFINITY};
  float lsum[4] = {0.f, 0.f, 0.f, 0.f};

  const int ntile = (qr0 + 16 + 31) >> 5;
  for (int kb = 0; kb < ntile; kb++) {
    const int kv0 = kb * 32;
    f32x4 s0 = (f32x4)0.f, s1 = (f32x4)0.f;
#pragma unroll
    for (int t = 0; t < 4; t++) {
      bf16x8 bk0 = *(const bf16x8*)(Kt + base + (size_t)(kv0 + lc) * DH + t * 32 + lr * 8);
      bf16x8 bk1 = *(const bf16x8*)(Kt + base + (size_t)(kv0 + 16 + lc) * DH + t * 32 + lr * 8);
      s0 = __builtin_amdgcn_mfma_f32_16x16x32_bf16(aq[t], bk0, s0, 0, 0, 0);
      s1 = __builtin_amdgcn_mfma_f32_16x16x32_bf16(aq[t], bk1, s1, 0, 0, 0);
    }
    float fsc[4];
#pragma unroll
    for (int r = 0; r < 4; r++) {
      const int row = qr0 + lr * 4 + r;
      float v0 = (kv0 + lc <= row) ? s0[r] * scale : -INFINITY;
      float v1 = (kv0 + 16 + lc <= row) ? s1[r] * scale : -INFINITY;
      float tm = fmaxf(v0, v1);
#pragma unroll
      for (int off = 1; off < 16; off <<= 1) tm = fmaxf(tm, __shfl_xor(tm, off, 64));
      const float mn = fmaxf(mrow[r], tm);
      const float fr = __expf(mrow[r] - mn);
      mrow[r] = mn;
      const float p0 = __expf(v0 - mn);
      const float p1 = __expf(v1 - mn);
      float ps = p0 + p1;
#pragma unroll
      for (int off = 1; off < 16; off <<= 1) ps += __shfl_xor(ps, off, 64);
      lsum[r] = lsum[r] * fr + ps;
      fsc[r] = fr;
      lP[w][(lr * 4 + r) * 32 + lc] = f2bf(p0);
      lP[w][(lr * 4 + r) * 32 + 16 + lc] = f2bf(p1);
    }
#pragma unroll
    for (int dt = 0; dt < 8; dt++)
#pragma unroll
      for (int r = 0; r < 4; r++) acc[dt][r] *= fsc[r];
    asm volatile("s_waitcnt lgkmcnt(0)" ::: "memory");
    bf16x8 pa = *(const bf16x8*)(&lP[w][lc * 32 + lr * 8]);
#pragma unroll
    for (int dt = 0; dt < 8; dt++) {
      bf16x8 bv = *(const bf16x8*)(VT + ((size_t)bh * DH + dt * 16 + lc) * S + kv0 + lr * 8);
      acc[dt] = __builtin_amdgcn_mfma_f32_16x16x32_bf16(pa, bv, acc[dt], 0, 0, 0);
    }
  }
#pragma unroll
  for (int dt = 0; dt < 8; dt++)
#pragma unroll
    for (int r = 0; r < 4; r++) {
      const int spos = qr0 + lr * 4 + r;
      const float ov = acc[dt][r] / lsum[r];
      O[((size_t)(b * S + spos) * H + h) * DH + dt * 16 + lc] = f2bf(ov);
    }
}

extern "C" void kernel_launch(void* const* d_in, const int* in_sizes, int n_in,
                              void* d_out, int out_size, void* d_ws, size_t ws_size,
                              hipStream_t stream) {
  const float* x    = (const float*)d_in[0];
  const float* cosT = (const float*)d_in[1];
  const float* sinT = (const float*)d_in[2];
  const float* Wqkv = (const float*)d_in[3];
  const float* bqkv = (const float*)d_in[4];
  const float* Wout = (const float*)d_in[5];
  const float* bout = (const float*)d_in[6];

  char* ws = (char*)d_ws;
  // ws layout (96 MB total):
  //   [0,32MB)   xbf  (x in bf16)  -- reused later as O (attention output, bf16)
  //   [32,56MB)  WqkvT (6144x2048 bf16, B^T layout)
  //   [56,64MB)  WoutT (2048x2048 bf16, B^T layout)
  //   [64,96MB)  VT    (b,h,d,s bf16)
  unsigned short* xbf   = (unsigned short*)(ws);
  unsigned short* WqkvT = (unsigned short*)(ws + ((size_t)32 << 20));
  unsigned short* WoutT = (unsigned short*)(ws + ((size_t)56 << 20));
  unsigned short* VTb   = (unsigned short*)(ws + ((size_t)64 << 20));
  // Q,K parked in d_out (64MB f32) -- dead before the final GEMM overwrites d_out
  unsigned short* Qb = (unsigned short*)d_out;
  unsigned short* Kb = (unsigned short*)d_out + (size_t)M * D;
  unsigned short* Ob = xbf;

  cvt_kernel<<<M * D / 1024, 256, 0, stream>>>(x, xbf);
  transpose_kernel<<<dim3(N3 / 32, D / 32), dim3(32, 8), 0, stream>>>(Wqkv, WqkvT, D, N3);
  transpose_kernel<<<dim3(D / 32, D / 32), dim3(32, 8), 0, stream>>>(Wout, WoutT, D, D);
  gemm_bt<0><<<dim3(M / 128, N3 / 128), 256, 0, stream>>>(xbf, WqkvT, bqkv, nullptr,
                                                          Qb, Kb, VTb, N3, D);
  rope_kernel<<<(B * H * S * 16) / 256, 256, 0, stream>>>(Qb, cosT, sinT);
  rope_kernel<<<(B * H * S * 16) / 256, 256, 0, stream>>>(Kb, cosT, sinT);
  attn_kernel<<<B * H * (S / 64), 256, 0, stream>>>(Qb, Kb, VTb, Ob);
  gemm_bt<1><<<dim3(M / 128, D / 128), 256, 0, stream>>>(Ob, WoutT, bout, (float*)d_out,
                                                         nullptr, nullptr, nullptr, D, D);
}

// Round 2
// 778.166 us; speedup vs baseline: 1.8050x; 1.8050x over previous
//
#include <hip/hip_runtime.h>
#include <hip/hip_bf16.h>
#include <math.h>

typedef __attribute__((ext_vector_type(8))) short bf16x8;
typedef __attribute__((ext_vector_type(4))) float f32x4;
typedef __attribute__((ext_vector_type(16))) float f32x16;
typedef __attribute__((ext_vector_type(8))) unsigned short u16x8;
typedef __attribute__((ext_vector_type(4))) unsigned short u16x4;

static constexpr int B = 4, S = 2048, D = 2048, H = 16, DH = 128;
static constexpr int N3 = 3 * D;   // 6144
static constexpr int M = B * S;    // 8192

__device__ __forceinline__ unsigned short f2bf(float f) {
  unsigned u = __float_as_uint(f);
  u += 0x7fffu + ((u >> 16) & 1u);
  return (unsigned short)(u >> 16);
}
__device__ __forceinline__ float bf2f(unsigned short b) {
  return __uint_as_float(((unsigned)b) << 16);
}

// ---------------- elementwise f32 -> bf16 convert (vectorized) ----------------
__global__ __launch_bounds__(256) void cvt_kernel(const float* __restrict__ in,
                                                  unsigned short* __restrict__ out) {
  size_t i = (size_t)blockIdx.x * 256 + threadIdx.x;
  f32x4 v = *(const f32x4*)(in + i * 4);
  u16x4 o;
  o[0] = f2bf(v[0]); o[1] = f2bf(v[1]); o[2] = f2bf(v[2]); o[3] = f2bf(v[3]);
  *(u16x4*)(out + i * 4) = o;
}

// ---------------- tiled transpose-convert: W (K,N) f32 -> WT (N,K) bf16 ----------------
__global__ __launch_bounds__(256) void transpose_kernel(const float* __restrict__ W,
                                                        unsigned short* __restrict__ WT,
                                                        int K, int N) {
  __shared__ float t[32][33];
  int tx = threadIdx.x, ty = threadIdx.y;
  int n0 = blockIdx.x * 32, k0 = blockIdx.y * 32;
#pragma unroll
  for (int i = 0; i < 4; i++)
    t[ty + i * 8][tx] = W[(size_t)(k0 + ty + i * 8) * N + n0 + tx];
  __syncthreads();
#pragma unroll
  for (int i = 0; i < 4; i++)
    WT[(size_t)(n0 + ty + i * 8) * K + k0 + tx] = f2bf(t[tx][ty + i * 8]);
}

// ---------------- async global->LDS helper ----------------
__device__ __forceinline__ void gload_lds(const void* g, void* l) {
  __builtin_amdgcn_global_load_lds((const __attribute__((address_space(1))) void*)g,
                                   (__attribute__((address_space(3))) void*)l, 16, 0, 0);
}

// ---------------- bf16 MFMA GEMM: C = A(M,K) * Bt(N,K)^T + bias ----------------
template <int EPI>
__global__ __launch_bounds__(256) void gemm_bt(
    const unsigned short* __restrict__ A, const unsigned short* __restrict__ Bt,
    const float* __restrict__ bias, float* __restrict__ Cf,
    unsigned short* __restrict__ Qp, unsigned short* __restrict__ Kp,
    unsigned short* __restrict__ VTp, int Nn, int Kk) {
  __shared__ __align__(16) unsigned short lA[128 * 32];
  __shared__ __align__(16) unsigned short lB[128 * 32];
  const int tid = threadIdx.x;
  const int l = tid & 63;
  const int w = tid >> 6;
  const int lr = l >> 4, lc = l & 15;
  const int wr = w >> 1, wc = w & 1;
  const int bm = blockIdx.x, bn = blockIdx.y;

  f32x4 acc[4][4];
#pragma unroll
  for (int m = 0; m < 4; m++)
#pragma unroll
    for (int n = 0; n < 4; n++) acc[m][n] = (f32x4)0.f;

  const int srow = tid >> 2;        // 0..63
  const int sk = (tid & 3) * 8;     // 0,8,16,24
  const unsigned short* Ab = A + (size_t)(bm * 128 + srow) * Kk + sk;
  const unsigned short* Bb = Bt + (size_t)(bn * 128 + srow) * Kk + sk;
  unsigned short* lA0 = lA + (size_t)tid * 8;
  unsigned short* lB0 = lB + (size_t)tid * 8;

  for (int kt = 0; kt < Kk; kt += 32) {
    __syncthreads();
    gload_lds(Ab + kt, lA0);
    gload_lds(Ab + (size_t)64 * Kk + kt, lA0 + 256 * 8);
    gload_lds(Bb + kt, lB0);
    gload_lds(Bb + (size_t)64 * Kk + kt, lB0 + 256 * 8);
    __syncthreads();
    bf16x8 af[4], bfr[4];
#pragma unroll
    for (int m = 0; m < 4; m++)
      af[m] = *(const bf16x8*)(lA + (wr * 64 + m * 16 + lc) * 32 + lr * 8);
#pragma unroll
    for (int n = 0; n < 4; n++)
      bfr[n] = *(const bf16x8*)(lB + (wc * 64 + n * 16 + lc) * 32 + lr * 8);
#pragma unroll
    for (int m = 0; m < 4; m++)
#pragma unroll
      for (int n = 0; n < 4; n++)
        acc[m][n] = __builtin_amdgcn_mfma_f32_16x16x32_bf16(af[m], bfr[n], acc[m][n], 0, 0, 0);
  }

#pragma unroll
  for (int m = 0; m < 4; m++) {
#pragma unroll
    for (int n = 0; n < 4; n++) {
      const int col = bn * 128 + wc * 64 + n * 16 + lc;
      const float bv = bias[col];
#pragma unroll
      for (int r = 0; r < 4; r++) {
        const int row = bm * 128 + wr * 64 + m * 16 + lr * 4 + r;
        const float v = acc[m][n][r] + bv;
        if (EPI == 0) {
          const unsigned short ob = f2bf(v);
          const int b = row >> 11, s = row & 2047;
          const int which = col >> 11, within = col & 2047;
          const int h = within >> 7, d = within & 127;
          const size_t bh = (size_t)(b * H + h);
          if (which == 0)      Qp[(bh * S + s) * DH + d] = ob;
          else if (which == 1) Kp[(bh * S + s) * DH + d] = ob;
          else                 VTp[(bh * DH + d) * S + s] = ob;
        } else {
          Cf[(size_t)row * Nn + col] = v;
        }
      }
    }
  }
}

// ---------------- RoPE in-place on (BH, S, DH) bf16, interleaved pairs ----------------
__global__ __launch_bounds__(256) void rope_kernel(unsigned short* __restrict__ T,
                                                   const float* __restrict__ cosT,
                                                   const float* __restrict__ sinT) {
  int t = blockIdx.x * 256 + threadIdx.x;
  int d8 = t & 15;
  int s = (t >> 4) & (S - 1);
  size_t off = (size_t)t * 8;
  u16x8 v = *(const u16x8*)(T + off);
  f32x4 c = *(const f32x4*)(cosT + (size_t)s * (DH / 2) + d8 * 4);
  f32x4 sn = *(const f32x4*)(sinT + (size_t)s * (DH / 2) + d8 * 4);
  u16x8 o;
#pragma unroll
  for (int j = 0; j < 4; j++) {
    float x1 = bf2f(v[2 * j]), x2 = bf2f(v[2 * j + 1]);
    o[2 * j]     = f2bf(x1 * c[j] - x2 * sn[j]);
    o[2 * j + 1] = f2bf(x1 * sn[j] + x2 * c[j]);
  }
  *(u16x8*)(T + off) = o;
}

// ---------------- flash attention v2: 8 waves/block, swapped QK^T, 32x32 MFMA ----------
// Each wave owns 32 q-rows; lane l handles q-row (l&31); lanes l and l+32 split the
// 32 k-values of each S^T tile. KVBLK=32. No LDS, no barriers. Strips paired for
// uniform causal work: block processes strip p and strip 7-p of one (b,h).
__global__ __launch_bounds__(512, 2) void attn2_kernel(
    const unsigned short* __restrict__ Q, const unsigned short* __restrict__ Kt,
    const unsigned short* __restrict__ VT, unsigned short* __restrict__ O) {
  const int tid = threadIdx.x;
  const int w = tid >> 6;       // wave 0..7
  const int l = tid & 63;
  const int ql = l & 31;
  const int hi = l >> 5;        // 0/1
  const int bh = blockIdx.x >> 2;
  const int pr = blockIdx.x & 3;
  const int b = bh >> 4, h = bh & 15;
  const size_t base = (size_t)bh * S * DH;
  const float cl = 0.088388347648318447f * 1.44269504088896341f;  // (1/sqrt(DH))*log2(e)

#pragma unroll
  for (int half = 0; half < 2; half++) {
    const int strip = (half == 0) ? pr : 7 - pr;
    const int qw0 = strip * 256 + w * 32;

    // Q B-frags: lane l holds Q[qw0+ql][t*16 + hi*8 + j], j=0..7
    bf16x8 qf[8];
    const unsigned short* qp = Q + base + (size_t)(qw0 + ql) * DH + hi * 8;
#pragma unroll
    for (int t = 0; t < 8; t++) qf[t] = *(const bf16x8*)(qp + t * 16);

    f32x16 acc[4];
#pragma unroll
    for (int mt = 0; mt < 4; mt++) acc[mt] = (f32x16)0.f;
    float m = -INFINITY, lsum = 0.f;

    const int ntile = qw0 / 32 + 1;
    for (int kb = 0; kb < ntile; kb++) {
      const int kv0 = kb * 32;
      // S^T = K_tile * Q_tile^T  (two accumulators to shorten the MFMA chain)
      f32x16 st0 = (f32x16)0.f, st1 = (f32x16)0.f;
      const unsigned short* kp = Kt + base + (size_t)(kv0 + ql) * DH + hi * 8;
#pragma unroll
      for (int t = 0; t < 4; t++) {
        st0 = __builtin_amdgcn_mfma_f32_32x32x16_bf16(
            *(const bf16x8*)(kp + (2 * t) * 16), qf[2 * t], st0, 0, 0, 0);
        st1 = __builtin_amdgcn_mfma_f32_32x32x16_bf16(
            *(const bf16x8*)(kp + (2 * t + 1) * 16), qf[2 * t + 1], st1, 0, 0, 0);
      }
      float sv[16];
#pragma unroll
      for (int r = 0; r < 16; r++) sv[r] = st0[r] + st1[r];
      if (kb == ntile - 1) {  // diagonal tile: mask k_local > ql
#pragma unroll
        for (int r = 0; r < 16; r++) {
          const int klocal = (r & 3) + 8 * (r >> 2) + 4 * hi;
          sv[r] = (klocal > ql) ? -INFINITY : sv[r];
        }
      }
      // row max: 15 in-lane + 1 cross-pair
      float smax = sv[0];
#pragma unroll
      for (int r = 1; r < 16; r++) smax = fmaxf(smax, sv[r]);
      smax = fmaxf(smax, __shfl_xor(smax, 32));

      float fr = 1.f;
      if (!__all((smax - m) * cl <= 8.0f)) {   // defer-max: rescale only when needed
        const float mn = fmaxf(m, smax);
        fr = exp2f((m - mn) * cl);
        m = mn;
#pragma unroll
        for (int mt = 0; mt < 4; mt++)
#pragma unroll
          for (int r = 0; r < 16; r++) acc[mt][r] *= fr;
      }
      float p[16];
      float ps = 0.f;
#pragma unroll
      for (int r = 0; r < 16; r++) {
        p[r] = exp2f((sv[r] - m) * cl);
        ps += p[r];
      }
      lsum = lsum * fr + ps + __shfl_xor(ps, 32);

      // pack p -> bf16 words: W[2q]   = (p[4q+1],p[4q])   -> k = 8q+4hi+{0,1}
      //                       W[2q+1] = (p[4q+3],p[4q+2]) -> k = 8q+4hi+{2,3}
      unsigned W[8];
#pragma unroll
      for (int qd = 0; qd < 4; qd++) {
        W[2 * qd]     = (unsigned)f2bf(p[4 * qd])     | ((unsigned)f2bf(p[4 * qd + 1]) << 16);
        W[2 * qd + 1] = (unsigned)f2bf(p[4 * qd + 2]) | ((unsigned)f2bf(p[4 * qd + 3]) << 16);
      }
      // PV: O^T += V^T * P^T, two K-steps of 16
#pragma unroll
      for (int t = 0; t < 2; t++) {
        const unsigned s0 = hi ? W[4 * t] : W[4 * t + 2];
        const unsigned s1 = hi ? W[4 * t + 1] : W[4 * t + 3];
        const unsigned r0 = __shfl_xor((int)s0, 32);
        const unsigned r1 = __shfl_xor((int)s1, 32);
        union { unsigned u[4]; bf16x8 v; } pf;
        if (hi == 0) { pf.u[0] = W[4 * t];     pf.u[1] = W[4 * t + 1]; pf.u[2] = r0; pf.u[3] = r1; }
        else         { pf.u[0] = r0;           pf.u[1] = r1;           pf.u[2] = W[4 * t + 2]; pf.u[3] = W[4 * t + 3]; }
#pragma unroll
        for (int mt = 0; mt < 4; mt++) {
          const bf16x8 vf = *(const bf16x8*)(VT + ((size_t)bh * DH + mt * 32 + ql) * S +
                                             kv0 + 16 * t + 8 * hi);
          acc[mt] = __builtin_amdgcn_mfma_f32_32x32x16_bf16(vf, pf.v, acc[mt], 0, 0, 0);
        }
      }
    }

    // epilogue: O^T[dh][q] / lsum -> O (b, s, h, dh); reg r=4g+j -> dh = mt*32+8g+4hi+j
    const float inv = 1.f / lsum;
    const int s_glob = qw0 + ql;
    unsigned short* op = O + ((size_t)(b * S + s_glob) * H + h) * DH;
#pragma unroll
    for (int mt = 0; mt < 4; mt++)
#pragma unroll
      for (int g = 0; g < 4; g++) {
        u16x4 ov;
#pragma unroll
        for (int j = 0; j < 4; j++) ov[j] = f2bf(acc[mt][4 * g + j] * inv);
        *(u16x4*)(op + mt * 32 + 8 * g + 4 * hi) = ov;
      }
  }
}

extern "C" void kernel_launch(void* const* d_in, const int* in_sizes, int n_in,
                              void* d_out, int out_size, void* d_ws, size_t ws_size,
                              hipStream_t stream) {
  const float* x    = (const float*)d_in[0];
  const float* cosT = (const float*)d_in[1];
  const float* sinT = (const float*)d_in[2];
  const float* Wqkv = (const float*)d_in[3];
  const float* bqkv = (const float*)d_in[4];
  const float* Wout = (const float*)d_in[5];
  const float* bout = (const float*)d_in[6];

  char* ws = (char*)d_ws;
  unsigned short* xbf   = (unsigned short*)(ws);
  unsigned short* WqkvT = (unsigned short*)(ws + ((size_t)32 << 20));
  unsigned short* WoutT = (unsigned short*)(ws + ((size_t)56 << 20));
  unsigned short* VTb   = (unsigned short*)(ws + ((size_t)64 << 20));
  unsigned short* Qb = (unsigned short*)d_out;
  unsigned short* Kb = (unsigned short*)d_out + (size_t)M * D;
  unsigned short* Ob = xbf;

  cvt_kernel<<<M * D / 1024, 256, 0, stream>>>(x, xbf);
  transpose_kernel<<<dim3(N3 / 32, D / 32), dim3(32, 8), 0, stream>>>(Wqkv, WqkvT, D, N3);
  transpose_kernel<<<dim3(D / 32, D / 32), dim3(32, 8), 0, stream>>>(Wout, WoutT, D, D);
  gemm_bt<0><<<dim3(M / 128, N3 / 128), 256, 0, stream>>>(xbf, WqkvT, bqkv, nullptr,
                                                          Qb, Kb, VTb, N3, D);
  rope_kernel<<<(B * H * S * 16) / 256, 256, 0, stream>>>(Qb, cosT, sinT);
  rope_kernel<<<(B * H * S * 16) / 256, 256, 0, stream>>>(Kb, cosT, sinT);
  attn2_kernel<<<B * H * 4, 512, 0, stream>>>(Qb, Kb, VTb, Ob);
  gemm_bt<1><<<dim3(M / 128, D / 128), 256, 0, stream>>>(Ob, WoutT, bout, (float*)d_out,
                                                         nullptr, nullptr, nullptr, D, D);
}

// Round 3
// 580.844 us; speedup vs baseline: 2.4182x; 1.3397x over previous
//
#include <hip/hip_runtime.h>
#include <hip/hip_bf16.h>
#include <math.h>

typedef __attribute__((ext_vector_type(8))) short bf16x8;
typedef __attribute__((ext_vector_type(4))) float f32x4;
typedef __attribute__((ext_vector_type(16))) float f32x16;
typedef __attribute__((ext_vector_type(8))) unsigned short u16x8;
typedef __attribute__((ext_vector_type(4))) unsigned short u16x4;

static constexpr int B = 4, S = 2048, D = 2048, H = 16, DH = 128;
static constexpr int N3 = 3 * D;   // 6144
static constexpr int M = B * S;    // 8192

__device__ __forceinline__ unsigned short f2bf(float f) {
  unsigned u = __float_as_uint(f);
  u += 0x7fffu + ((u >> 16) & 1u);
  return (unsigned short)(u >> 16);
}
__device__ __forceinline__ float bf2f(unsigned short b) {
  return __uint_as_float(((unsigned)b) << 16);
}

// ---------------- elementwise f32 -> bf16 convert (vectorized) ----------------
__global__ __launch_bounds__(256) void cvt_kernel(const float* __restrict__ in,
                                                  unsigned short* __restrict__ out) {
  size_t i = (size_t)blockIdx.x * 256 + threadIdx.x;
  f32x4 v = *(const f32x4*)(in + i * 4);
  u16x4 o;
  o[0] = f2bf(v[0]); o[1] = f2bf(v[1]); o[2] = f2bf(v[2]); o[3] = f2bf(v[3]);
  *(u16x4*)(out + i * 4) = o;
}

// ---------------- tiled transpose-convert: W (K,N) f32 -> WT (N,K) bf16 ----------------
__global__ __launch_bounds__(256) void transpose_kernel(const float* __restrict__ W,
                                                        unsigned short* __restrict__ WT,
                                                        int K, int N) {
  __shared__ float t[32][33];
  int tx = threadIdx.x, ty = threadIdx.y;
  int n0 = blockIdx.x * 32, k0 = blockIdx.y * 32;
#pragma unroll
  for (int i = 0; i < 4; i++)
    t[ty + i * 8][tx] = W[(size_t)(k0 + ty + i * 8) * N + n0 + tx];
  __syncthreads();
#pragma unroll
  for (int i = 0; i < 4; i++)
    WT[(size_t)(n0 + ty + i * 8) * K + k0 + tx] = f2bf(t[tx][ty + i * 8]);
}

// ---------------- async global->LDS helper ----------------
__device__ __forceinline__ void gload_lds(const void* g, void* l) {
  __builtin_amdgcn_global_load_lds((const __attribute__((address_space(1))) void*)g,
                                   (__attribute__((address_space(3))) void*)l, 16, 0, 0);
}

// ---------------- bf16 MFMA GEMM: C = A(M,K) * Bt(N,K)^T + bias ----------------
template <int EPI>
__global__ __launch_bounds__(256) void gemm_bt(
    const unsigned short* __restrict__ A, const unsigned short* __restrict__ Bt,
    const float* __restrict__ bias, float* __restrict__ Cf,
    unsigned short* __restrict__ Qp, unsigned short* __restrict__ Kp,
    unsigned short* __restrict__ VTp, int Nn, int Kk) {
  __shared__ __align__(16) unsigned short lA[128 * 32];
  __shared__ __align__(16) unsigned short lB[128 * 32];
  const int tid = threadIdx.x;
  const int l = tid & 63;
  const int w = tid >> 6;
  const int lr = l >> 4, lc = l & 15;
  const int wr = w >> 1, wc = w & 1;
  const int bm = blockIdx.x, bn = blockIdx.y;

  f32x4 acc[4][4];
#pragma unroll
  for (int m = 0; m < 4; m++)
#pragma unroll
    for (int n = 0; n < 4; n++) acc[m][n] = (f32x4)0.f;

  const int srow = tid >> 2;
  const int sk = (tid & 3) * 8;
  const unsigned short* Ab = A + (size_t)(bm * 128 + srow) * Kk + sk;
  const unsigned short* Bb = Bt + (size_t)(bn * 128 + srow) * Kk + sk;
  unsigned short* lA0 = lA + (size_t)tid * 8;
  unsigned short* lB0 = lB + (size_t)tid * 8;

  for (int kt = 0; kt < Kk; kt += 32) {
    __syncthreads();
    gload_lds(Ab + kt, lA0);
    gload_lds(Ab + (size_t)64 * Kk + kt, lA0 + 256 * 8);
    gload_lds(Bb + kt, lB0);
    gload_lds(Bb + (size_t)64 * Kk + kt, lB0 + 256 * 8);
    __syncthreads();
    bf16x8 af[4], bfr[4];
#pragma unroll
    for (int m = 0; m < 4; m++)
      af[m] = *(const bf16x8*)(lA + (wr * 64 + m * 16 + lc) * 32 + lr * 8);
#pragma unroll
    for (int n = 0; n < 4; n++)
      bfr[n] = *(const bf16x8*)(lB + (wc * 64 + n * 16 + lc) * 32 + lr * 8);
#pragma unroll
    for (int m = 0; m < 4; m++)
#pragma unroll
      for (int n = 0; n < 4; n++)
        acc[m][n] = __builtin_amdgcn_mfma_f32_16x16x32_bf16(af[m], bfr[n], acc[m][n], 0, 0, 0);
  }

#pragma unroll
  for (int m = 0; m < 4; m++) {
#pragma unroll
    for (int n = 0; n < 4; n++) {
      const int col = bn * 128 + wc * 64 + n * 16 + lc;
      const float bv = bias[col];
#pragma unroll
      for (int r = 0; r < 4; r++) {
        const int row = bm * 128 + wr * 64 + m * 16 + lr * 4 + r;
        const float v = acc[m][n][r] + bv;
        if (EPI == 0) {
          const unsigned short ob = f2bf(v);
          const int b = row >> 11, s = row & 2047;
          const int which = col >> 11, within = col & 2047;
          const int h = within >> 7, d = within & 127;
          const size_t bh = (size_t)(b * H + h);
          if (which == 0)      Qp[(bh * S + s) * DH + d] = ob;
          else if (which == 1) Kp[(bh * S + s) * DH + d] = ob;
          else                 VTp[(bh * DH + d) * S + s] = ob;
        } else {
          Cf[(size_t)row * Nn + col] = v;
        }
      }
    }
  }
}

// ---------------- RoPE in-place on (BH, S, DH) bf16, interleaved pairs ----------------
__global__ __launch_bounds__(256) void rope_kernel(unsigned short* __restrict__ T,
                                                   const float* __restrict__ cosT,
                                                   const float* __restrict__ sinT) {
  int t = blockIdx.x * 256 + threadIdx.x;
  int d8 = t & 15;
  int s = (t >> 4) & (S - 1);
  size_t off = (size_t)t * 8;
  u16x8 v = *(const u16x8*)(T + off);
  f32x4 c = *(const f32x4*)(cosT + (size_t)s * (DH / 2) + d8 * 4);
  f32x4 sn = *(const f32x4*)(sinT + (size_t)s * (DH / 2) + d8 * 4);
  u16x8 o;
#pragma unroll
  for (int j = 0; j < 4; j++) {
    float x1 = bf2f(v[2 * j]), x2 = bf2f(v[2 * j + 1]);
    o[2 * j]     = f2bf(x1 * c[j] - x2 * sn[j]);
    o[2 * j + 1] = f2bf(x1 * sn[j] + x2 * c[j]);
  }
  *(u16x8*)(T + off) = o;
}

// ---------------- flash attention v3: LDS-shared K/V tiles across 8 waves ----------
// Block = 512 threads = 8 waves x 32 q-rows -> one 256-row strip; block handles strips
// pr and 7-pr (uniform 72 tiles/block). Per KV tile (32 rows): K+V staged once to LDS
// (reg-staged, double-buffered, 1 barrier/tile). K tile [32][128] XOR-swizzled;
// V tile [128][32] with 80B-padded rows. Swapped QK^T, in-register softmax.
__global__ __launch_bounds__(512, 1) void attn3_kernel(
    const unsigned short* __restrict__ Q, const unsigned short* __restrict__ Kt,
    const unsigned short* __restrict__ VT, unsigned short* __restrict__ O) {
  __shared__ __align__(16) unsigned short lK[2][32 * 128];
  __shared__ __align__(16) unsigned short lV[2][128 * 40];
  const int tid = threadIdx.x;
  const int w = tid >> 6;       // wave 0..7
  const int l = tid & 63;
  const int ql = l & 31;
  const int hi = l >> 5;        // 0/1
  const int j = blockIdx.x;
  const int bh = ((j >> 3) & 7) * 8 + (j & 7);  // 4 blocks of one bh -> same XCD slot
  const int pr = j >> 6;                        // 0..3
  const int b = bh >> 4, h = bh & 15;
  const size_t base = (size_t)bh * S * DH;
  const float cl = 0.088388347648318447f * 1.44269504088896341f;  // (1/sqrt(DH))*log2e

  // staging constants
  const int kdst = (tid * 8) ^ (((tid >> 4) & 7) << 3);  // K LDS dest (ushort), swizzled
  const unsigned short* Kgb = Kt + base;                  // K tile kb at +kb*4096
  const int vdh = tid >> 2;                               // 0..127
  const int vc = (tid & 3) * 8;                           // 0,8,16,24
  const int vdst = vdh * 40 + vc;                         // 80B-padded rows
  const unsigned short* Vgr = VT + ((size_t)bh * DH + vdh) * S;
  const int sfix = (ql & 7) << 3;                         // K read swizzle

  for (int half = 0; half < 2; half++) {
    const int strip = half ? 7 - pr : pr;
    const int qw0 = strip * 256 + w * 32;

    bf16x8 qf[8];
    const unsigned short* qp = Q + base + (size_t)(qw0 + ql) * DH + hi * 8;
#pragma unroll
    for (int t = 0; t < 8; t++) qf[t] = *(const bf16x8*)(qp + t * 16);

    f32x16 acc[4];
#pragma unroll
    for (int mt = 0; mt < 4; mt++) acc[mt] = (f32x16)0.f;
    float m = -INFINITY, lsum = 0.f;

    const int ntb = 8 * (strip + 1);  // tiles this block iterates
    const int last = 8 * strip + w;   // this wave's diagonal tile index

    // prologue: stage tile 0 into buffer 0
    {
      f32x4 kr = *(const f32x4*)(Kgb + tid * 8);
      f32x4 vr = *(const f32x4*)(Vgr + vc);
      *(f32x4*)(&lK[0][kdst]) = kr;
      *(f32x4*)(&lV[0][vdst]) = vr;
      __syncthreads();
    }

    for (int kb = 0; kb < ntb; kb++) {
      const int cur = kb & 1;
      const bool more = (kb + 1 < ntb);
      f32x4 kr, vr;
      if (more) {  // issue next-tile loads early (latency hides under compute)
        kr = *(const f32x4*)(Kgb + (size_t)(kb + 1) * 4096 + tid * 8);
        vr = *(const f32x4*)(Vgr + (kb + 1) * 32 + vc);
      }
      if (kb <= last) {
        const int kv0 = kb * 32;
        const unsigned short* kbuf = lK[cur];
        const unsigned short* vbuf = lV[cur];
        // S^T = K_tile * Q_tile^T
        f32x16 st0 = (f32x16)0.f, st1 = (f32x16)0.f;
#pragma unroll
        for (int t = 0; t < 4; t++) {
          bf16x8 k0 = *(const bf16x8*)(kbuf + ((ql * 128 + (2 * t) * 16 + 8 * hi) ^ sfix));
          bf16x8 k1 = *(const bf16x8*)(kbuf + ((ql * 128 + (2 * t + 1) * 16 + 8 * hi) ^ sfix));
          st0 = __builtin_amdgcn_mfma_f32_32x32x16_bf16(k0, qf[2 * t], st0, 0, 0, 0);
          st1 = __builtin_amdgcn_mfma_f32_32x32x16_bf16(k1, qf[2 * t + 1], st1, 0, 0, 0);
        }
        float sv[16];
#pragma unroll
        for (int r = 0; r < 16; r++) sv[r] = st0[r] + st1[r];
        if (kb == last) {  // diagonal tile: mask k_local > ql
#pragma unroll
          for (int r = 0; r < 16; r++) {
            const int klocal = (r & 3) + 8 * (r >> 2) + 4 * hi;
            sv[r] = (klocal > ql) ? -INFINITY : sv[r];
          }
        }
        float smax = sv[0];
#pragma unroll
        for (int r = 1; r < 16; r++) smax = fmaxf(smax, sv[r]);
        smax = fmaxf(smax, __shfl_xor(smax, 32));

        float fr = 1.f;
        if (!__all((smax - m) * cl <= 8.0f)) {  // defer-max
          const float mn = fmaxf(m, smax);
          fr = exp2f((m - mn) * cl);
          m = mn;
#pragma unroll
          for (int mt = 0; mt < 4; mt++)
#pragma unroll
            for (int r = 0; r < 16; r++) acc[mt][r] *= fr;
        }
        float p[16];
        float ps = 0.f;
#pragma unroll
        for (int r = 0; r < 16; r++) {
          p[r] = exp2f((sv[r] - m) * cl);
          ps += p[r];
        }
        lsum = lsum * fr + ps + __shfl_xor(ps, 32);

        unsigned W[8];
#pragma unroll
        for (int qd = 0; qd < 4; qd++) {
          W[2 * qd]     = (unsigned)f2bf(p[4 * qd])     | ((unsigned)f2bf(p[4 * qd + 1]) << 16);
          W[2 * qd + 1] = (unsigned)f2bf(p[4 * qd + 2]) | ((unsigned)f2bf(p[4 * qd + 3]) << 16);
        }
#pragma unroll
        for (int t = 0; t < 2; t++) {
          const unsigned s0 = hi ? W[4 * t] : W[4 * t + 2];
          const unsigned s1 = hi ? W[4 * t + 1] : W[4 * t + 3];
          const unsigned r0 = __shfl_xor((int)s0, 32);
          const unsigned r1 = __shfl_xor((int)s1, 32);
          union { unsigned u[4]; bf16x8 v; } pf;
          if (hi == 0) { pf.u[0] = W[4 * t]; pf.u[1] = W[4 * t + 1]; pf.u[2] = r0; pf.u[3] = r1; }
          else         { pf.u[0] = r0; pf.u[1] = r1; pf.u[2] = W[4 * t + 2]; pf.u[3] = W[4 * t + 3]; }
#pragma unroll
          for (int mt = 0; mt < 4; mt++) {
            const bf16x8 vf = *(const bf16x8*)(vbuf + (mt * 32 + ql) * 40 + 16 * t + 8 * hi);
            acc[mt] = __builtin_amdgcn_mfma_f32_32x32x16_bf16(vf, pf.v, acc[mt], 0, 0, 0);
          }
        }
        (void)kv0;
      }
      if (more) {  // write next tile into the other buffer
        *(f32x4*)(&lK[cur ^ 1][kdst]) = kr;
        *(f32x4*)(&lV[cur ^ 1][vdst]) = vr;
      }
      __syncthreads();
    }

    // epilogue: O^T[dh][q] / lsum -> O (b, s, h, dh)
    const float inv = 1.f / lsum;
    const int s_glob = qw0 + ql;
    unsigned short* op = O + ((size_t)(b * S + s_glob) * H + h) * DH;
#pragma unroll
    for (int mt = 0; mt < 4; mt++)
#pragma unroll
      for (int g = 0; g < 4; g++) {
        u16x4 ov;
#pragma unroll
        for (int jj = 0; jj < 4; jj++) ov[jj] = f2bf(acc[mt][4 * g + jj] * inv);
        *(u16x4*)(op + mt * 32 + 8 * g + 4 * hi) = ov;
      }
  }
}

extern "C" void kernel_launch(void* const* d_in, const int* in_sizes, int n_in,
                              void* d_out, int out_size, void* d_ws, size_t ws_size,
                              hipStream_t stream) {
  const float* x    = (const float*)d_in[0];
  const float* cosT = (const float*)d_in[1];
  const float* sinT = (const float*)d_in[2];
  const float* Wqkv = (const float*)d_in[3];
  const float* bqkv = (const float*)d_in[4];
  const float* Wout = (const float*)d_in[5];
  const float* bout = (const float*)d_in[6];

  char* ws = (char*)d_ws;
  unsigned short* xbf   = (unsigned short*)(ws);
  unsigned short* WqkvT = (unsigned short*)(ws + ((size_t)32 << 20));
  unsigned short* WoutT = (unsigned short*)(ws + ((size_t)56 << 20));
  unsigned short* VTb   = (unsigned short*)(ws + ((size_t)64 << 20));
  unsigned short* Qb = (unsigned short*)d_out;
  unsigned short* Kb = (unsigned short*)d_out + (size_t)M * D;
  unsigned short* Ob = xbf;

  cvt_kernel<<<M * D / 1024, 256, 0, stream>>>(x, xbf);
  transpose_kernel<<<dim3(N3 / 32, D / 32), dim3(32, 8), 0, stream>>>(Wqkv, WqkvT, D, N3);
  transpose_kernel<<<dim3(D / 32, D / 32), dim3(32, 8), 0, stream>>>(Wout, WoutT, D, D);
  gemm_bt<0><<<dim3(M / 128, N3 / 128), 256, 0, stream>>>(xbf, WqkvT, bqkv, nullptr,
                                                          Qb, Kb, VTb, N3, D);
  rope_kernel<<<(B * H * S * 16) / 256, 256, 0, stream>>>(Qb, cosT, sinT);
  rope_kernel<<<(B * H * S * 16) / 256, 256, 0, stream>>>(Kb, cosT, sinT);
  attn3_kernel<<<B * H * 4, 512, 0, stream>>>(Qb, Kb, VTb, Ob);
  gemm_bt<1><<<dim3(M / 128, D / 128), 256, 0, stream>>>(Ob, WoutT, bout, (float*)d_out,
                                                         nullptr, nullptr, nullptr, D, D);
}

// Round 4
// 528.069 us; speedup vs baseline: 2.6599x; 1.0999x over previous
//
#include <hip/hip_runtime.h>
#include <hip/hip_bf16.h>
#include <math.h>

typedef __attribute__((ext_vector_type(8))) short bf16x8;
typedef __attribute__((ext_vector_type(4))) float f32x4;
typedef __attribute__((ext_vector_type(16))) float f32x16;
typedef __attribute__((ext_vector_type(8))) unsigned short u16x8;
typedef __attribute__((ext_vector_type(4))) unsigned short u16x4;

static constexpr int B = 4, S = 2048, D = 2048, H = 16, DH = 128;
static constexpr int N3 = 3 * D;   // 6144
static constexpr int M = B * S;    // 8192

__device__ __forceinline__ unsigned short f2bf(float f) {
  unsigned u = __float_as_uint(f);
  u += 0x7fffu + ((u >> 16) & 1u);
  return (unsigned short)(u >> 16);
}
__device__ __forceinline__ float bf2f(unsigned short b) {
  return __uint_as_float(((unsigned)b) << 16);
}

// ---------------- elementwise f32 -> bf16 convert (vectorized) ----------------
__global__ __launch_bounds__(256) void cvt_kernel(const float* __restrict__ in,
                                                  unsigned short* __restrict__ out) {
  size_t i = (size_t)blockIdx.x * 256 + threadIdx.x;
  f32x4 v = *(const f32x4*)(in + i * 4);
  u16x4 o;
  o[0] = f2bf(v[0]); o[1] = f2bf(v[1]); o[2] = f2bf(v[2]); o[3] = f2bf(v[3]);
  *(u16x4*)(out + i * 4) = o;
}

// ---------------- tiled transpose-convert: W (K,N) f32 -> WT (N,K) bf16 ----------------
__global__ __launch_bounds__(256) void transpose_kernel(const float* __restrict__ W,
                                                        unsigned short* __restrict__ WT,
                                                        int K, int N) {
  __shared__ float t[32][33];
  int tx = threadIdx.x, ty = threadIdx.y;
  int n0 = blockIdx.x * 32, k0 = blockIdx.y * 32;
#pragma unroll
  for (int i = 0; i < 4; i++)
    t[ty + i * 8][tx] = W[(size_t)(k0 + ty + i * 8) * N + n0 + tx];
  __syncthreads();
#pragma unroll
  for (int i = 0; i < 4; i++)
    WT[(size_t)(n0 + ty + i * 8) * K + k0 + tx] = f2bf(t[tx][ty + i * 8]);
}

// ---------------- async global->LDS helper ----------------
__device__ __forceinline__ void gload_lds(const void* g, void* l) {
  __builtin_amdgcn_global_load_lds((const __attribute__((address_space(1))) void*)g,
                                   (__attribute__((address_space(3))) void*)l, 16, 0, 0);
}

// ---------------- bf16 MFMA GEMM, pipelined: C = A(M,2048) * Bt(N,2048)^T + bias -------
// BM=256, BN=128, BK=64. 512 threads = 8 waves (4 wr x 2 wc), per-wave 64x64 output.
// 3 LDS buffers (48KB each): compute tile t from buf[t%3], stage tile t+2 into
// buf[(t+2)%3] -- staging never writes a buffer being read. 2 phases per K-tile
// (one per K-half): 8 ds_read_b128 + 3 global_load_lds + 16 MFMA. Counted vmcnt(6)
// once per K-tile (in-flight = tile t+2's 6 loads). Raw s_barrier (no auto-drain).
// LDS granule swizzle g^=(row&7): applied on pre-swizzled global source + ds_read.
template <int EPI>
__global__ __launch_bounds__(512, 1) void gemm_bt(
    const unsigned short* __restrict__ A, const unsigned short* __restrict__ Bt,
    const float* __restrict__ bias, float* __restrict__ Cf,
    unsigned short* __restrict__ Qp, unsigned short* __restrict__ Kp,
    unsigned short* __restrict__ VTp, int Nn, int nbn) {
  __shared__ __align__(16) unsigned short lds[3 * 24576];  // 147456 B
  constexpr int NT = 32;  // K = 2048 / BK = 64
  const int tid = threadIdx.x;
  const int l = tid & 63;
  const int w = tid >> 6;
  const int lr = l >> 4, lc = l & 15;
  const int wr = w >> 1, wc = w & 1;

  // XCD-aware swizzle (nwg % 8 == 0), bm-major so each XCD chunk shares A in L2
  const int nwg = gridDim.x;
  const int cpx = nwg >> 3;
  const int wg = blockIdx.x;
  const int swz = (wg & 7) * cpx + (wg >> 3);
  const int bm = swz / nbn;
  const int bn = swz - bm * nbn;

  // stage source pointers (pre-swizzled: granule g within a 128B row XORed with row&7)
  const unsigned short* As[4];
  const unsigned short* Bs[2];
  int ldA[4], ldB[2];
#pragma unroll
  for (int i = 0; i < 4; i++) {
    const int g = i * 512 + tid;
    const int r = g >> 3;
    const int c8 = (g & 7) ^ (r & 7);
    As[i] = A + (size_t)(bm * 256 + r) * 2048 + c8 * 8;
    ldA[i] = g * 8;
  }
#pragma unroll
  for (int i = 0; i < 2; i++) {
    const int g = i * 512 + tid;
    const int r = g >> 3;
    const int c8 = (g & 7) ^ (r & 7);
    Bs[i] = Bt + (size_t)(bn * 128 + r) * 2048 + c8 * 8;
    ldB[i] = 16384 + g * 8;
  }

#define STAGE_HALF(t_, h_, bufb_)                              \
  do {                                                         \
    const int kt_ = (t_) * 64;                                 \
    unsigned short* ub_ = lds + (bufb_) * 24576;               \
    if ((h_) == 0) {                                           \
      gload_lds(As[0] + kt_, ub_ + ldA[0]);                    \
      gload_lds(As[1] + kt_, ub_ + ldA[1]);                    \
      gload_lds(Bs[0] + kt_, ub_ + ldB[0]);                    \
    } else {                                                   \
      gload_lds(As[2] + kt_, ub_ + ldA[2]);                    \
      gload_lds(As[3] + kt_, ub_ + ldA[3]);                    \
      gload_lds(Bs[1] + kt_, ub_ + ldB[1]);                    \
    }                                                          \
  } while (0)

  f32x4 acc[4][4];
#pragma unroll
  for (int m = 0; m < 4; m++)
#pragma unroll
    for (int n = 0; n < 4; n++) acc[m][n] = (f32x4)0.f;

  // prologue: stage tiles 0,1
  STAGE_HALF(0, 0, 0); STAGE_HALF(0, 1, 0);
  STAGE_HALF(1, 0, 1); STAGE_HALF(1, 1, 1);
  __builtin_amdgcn_sched_barrier(0);
  asm volatile("s_waitcnt vmcnt(6)" ::: "memory");   // tile 0 landed (own stages)
  __builtin_amdgcn_s_barrier();                      // publish cross-wave
  __builtin_amdgcn_sched_barrier(0);

  int cur = 0;
  for (int t = 0; t < NT; t++) {
    const int s2 = (cur >= 1) ? cur - 1 : cur + 2;   // (t+2)%3
    unsigned short* buf = lds + cur * 24576;
    const bool stg = (t + 2) < NT;
#pragma unroll
    for (int kh = 0; kh < 2; kh++) {
      const int ko = (kh * 32 + lr * 8) ^ ((lc & 7) << 3);
      bf16x8 af[4], bfr[4];
#pragma unroll
      for (int m = 0; m < 4; m++)
        af[m] = *(const bf16x8*)(buf + (wr * 64 + m * 16 + lc) * 64 + ko);
#pragma unroll
      for (int n = 0; n < 4; n++)
        bfr[n] = *(const bf16x8*)(buf + 16384 + (wc * 64 + n * 16 + lc) * 64 + ko);
      if (stg) STAGE_HALF(t + 2, kh, s2);
      __builtin_amdgcn_sched_barrier(0);
      __builtin_amdgcn_s_barrier();
      asm volatile("s_waitcnt lgkmcnt(0)" ::: "memory");
      __builtin_amdgcn_sched_barrier(0);
      __builtin_amdgcn_s_setprio(1);
#pragma unroll
      for (int m = 0; m < 4; m++)
#pragma unroll
        for (int n = 0; n < 4; n++)
          acc[m][n] = __builtin_amdgcn_mfma_f32_16x16x32_bf16(af[m], bfr[n], acc[m][n], 0, 0, 0);
      __builtin_amdgcn_s_setprio(0);
      __builtin_amdgcn_sched_barrier(0);
      if (kh == 1) {
        if (stg) asm volatile("s_waitcnt vmcnt(6)" ::: "memory");  // tile t+1 landed
        else     asm volatile("s_waitcnt vmcnt(0)" ::: "memory");
        __builtin_amdgcn_sched_barrier(0);
      }
      __builtin_amdgcn_s_barrier();
      __builtin_amdgcn_sched_barrier(0);
    }
    cur = (cur == 2) ? 0 : cur + 1;
  }
#undef STAGE_HALF

#pragma unroll
  for (int m = 0; m < 4; m++) {
#pragma unroll
    for (int n = 0; n < 4; n++) {
      const int col = bn * 128 + wc * 64 + n * 16 + lc;
      const float bv = bias[col];
#pragma unroll
      for (int r = 0; r < 4; r++) {
        const int row = bm * 256 + wr * 64 + m * 16 + lr * 4 + r;
        const float v = acc[m][n][r] + bv;
        if (EPI == 0) {
          const unsigned short ob = f2bf(v);
          const int b = row >> 11, s = row & 2047;
          const int which = col >> 11, within = col & 2047;
          const int h = within >> 7, d = within & 127;
          const size_t bh = (size_t)(b * H + h);
          if (which == 0)      Qp[(bh * S + s) * DH + d] = ob;
          else if (which == 1) Kp[(bh * S + s) * DH + d] = ob;
          else                 VTp[(bh * DH + d) * S + s] = ob;
        } else {
          Cf[(size_t)row * Nn + col] = v;
        }
      }
    }
  }
}

// ---------------- RoPE in-place on (BH, S, DH) bf16, interleaved pairs ----------------
__global__ __launch_bounds__(256) void rope_kernel(unsigned short* __restrict__ T,
                                                   const float* __restrict__ cosT,
                                                   const float* __restrict__ sinT) {
  int t = blockIdx.x * 256 + threadIdx.x;
  int d8 = t & 15;
  int s = (t >> 4) & (S - 1);
  size_t off = (size_t)t * 8;
  u16x8 v = *(const u16x8*)(T + off);
  f32x4 c = *(const f32x4*)(cosT + (size_t)s * (DH / 2) + d8 * 4);
  f32x4 sn = *(const f32x4*)(sinT + (size_t)s * (DH / 2) + d8 * 4);
  u16x8 o;
#pragma unroll
  for (int j = 0; j < 4; j++) {
    float x1 = bf2f(v[2 * j]), x2 = bf2f(v[2 * j + 1]);
    o[2 * j]     = f2bf(x1 * c[j] - x2 * sn[j]);
    o[2 * j + 1] = f2bf(x1 * sn[j] + x2 * c[j]);
  }
  *(u16x8*)(T + off) = o;
}

// ---------------- flash attention v3: LDS-shared K/V tiles across 8 waves ----------
__global__ __launch_bounds__(512, 1) void attn3_kernel(
    const unsigned short* __restrict__ Q, const unsigned short* __restrict__ Kt,
    const unsigned short* __restrict__ VT, unsigned short* __restrict__ O) {
  __shared__ __align__(16) unsigned short lK[2][32 * 128];
  __shared__ __align__(16) unsigned short lV[2][128 * 40];
  const int tid = threadIdx.x;
  const int w = tid >> 6;       // wave 0..7
  const int l = tid & 63;
  const int ql = l & 31;
  const int hi = l >> 5;        // 0/1
  const int j = blockIdx.x;
  const int bh = ((j >> 3) & 7) * 8 + (j & 7);
  const int pr = j >> 6;                        // 0..3
  const int b = bh >> 4, h = bh & 15;
  const size_t base = (size_t)bh * S * DH;
  const float cl = 0.088388347648318447f * 1.44269504088896341f;  // (1/sqrt(DH))*log2e

  const int kdst = (tid * 8) ^ (((tid >> 4) & 7) << 3);
  const unsigned short* Kgb = Kt + base;
  const int vdh = tid >> 2;
  const int vc = (tid & 3) * 8;
  const int vdst = vdh * 40 + vc;
  const unsigned short* Vgr = VT + ((size_t)bh * DH + vdh) * S;
  const int sfix = (ql & 7) << 3;

  for (int half = 0; half < 2; half++) {
    const int strip = half ? 7 - pr : pr;
    const int qw0 = strip * 256 + w * 32;

    bf16x8 qf[8];
    const unsigned short* qp = Q + base + (size_t)(qw0 + ql) * DH + hi * 8;
#pragma unroll
    for (int t = 0; t < 8; t++) qf[t] = *(const bf16x8*)(qp + t * 16);

    f32x16 acc[4];
#pragma unroll
    for (int mt = 0; mt < 4; mt++) acc[mt] = (f32x16)0.f;
    float m = -INFINITY, lsum = 0.f;

    const int ntb = 8 * (strip + 1);
    const int last = 8 * strip + w;

    {
      f32x4 kr = *(const f32x4*)(Kgb + tid * 8);
      f32x4 vr = *(const f32x4*)(Vgr + vc);
      *(f32x4*)(&lK[0][kdst]) = kr;
      *(f32x4*)(&lV[0][vdst]) = vr;
      __syncthreads();
    }

    for (int kb = 0; kb < ntb; kb++) {
      const int cur = kb & 1;
      const bool more = (kb + 1 < ntb);
      f32x4 kr, vr;
      if (more) {
        kr = *(const f32x4*)(Kgb + (size_t)(kb + 1) * 4096 + tid * 8);
        vr = *(const f32x4*)(Vgr + (kb + 1) * 32 + vc);
      }
      if (kb <= last) {
        const unsigned short* kbuf = lK[cur];
        const unsigned short* vbuf = lV[cur];
        f32x16 st0 = (f32x16)0.f, st1 = (f32x16)0.f;
#pragma unroll
        for (int t = 0; t < 4; t++) {
          bf16x8 k0 = *(const bf16x8*)(kbuf + ((ql * 128 + (2 * t) * 16 + 8 * hi) ^ sfix));
          bf16x8 k1 = *(const bf16x8*)(kbuf + ((ql * 128 + (2 * t + 1) * 16 + 8 * hi) ^ sfix));
          st0 = __builtin_amdgcn_mfma_f32_32x32x16_bf16(k0, qf[2 * t], st0, 0, 0, 0);
          st1 = __builtin_amdgcn_mfma_f32_32x32x16_bf16(k1, qf[2 * t + 1], st1, 0, 0, 0);
        }
        float sv[16];
#pragma unroll
        for (int r = 0; r < 16; r++) sv[r] = st0[r] + st1[r];
        if (kb == last) {
#pragma unroll
          for (int r = 0; r < 16; r++) {
            const int klocal = (r & 3) + 8 * (r >> 2) + 4 * hi;
            sv[r] = (klocal > ql) ? -INFINITY : sv[r];
          }
        }
        float smax = sv[0];
#pragma unroll
        for (int r = 1; r < 16; r++) smax = fmaxf(smax, sv[r]);
        smax = fmaxf(smax, __shfl_xor(smax, 32));

        float fr = 1.f;
        if (!__all((smax - m) * cl <= 8.0f)) {
          const float mn = fmaxf(m, smax);
          fr = exp2f((m - mn) * cl);
          m = mn;
#pragma unroll
          for (int mt = 0; mt < 4; mt++)
#pragma unroll
            for (int r = 0; r < 16; r++) acc[mt][r] *= fr;
        }
        float p[16];
        float ps = 0.f;
#pragma unroll
        for (int r = 0; r < 16; r++) {
          p[r] = exp2f((sv[r] - m) * cl);
          ps += p[r];
        }
        lsum = lsum * fr + ps + __shfl_xor(ps, 32);

        unsigned W[8];
#pragma unroll
        for (int qd = 0; qd < 4; qd++) {
          W[2 * qd]     = (unsigned)f2bf(p[4 * qd])     | ((unsigned)f2bf(p[4 * qd + 1]) << 16);
          W[2 * qd + 1] = (unsigned)f2bf(p[4 * qd + 2]) | ((unsigned)f2bf(p[4 * qd + 3]) << 16);
        }
#pragma unroll
        for (int t = 0; t < 2; t++) {
          const unsigned s0 = hi ? W[4 * t] : W[4 * t + 2];
          const unsigned s1 = hi ? W[4 * t + 1] : W[4 * t + 3];
          const unsigned r0 = __shfl_xor((int)s0, 32);
          const unsigned r1 = __shfl_xor((int)s1, 32);
          union { unsigned u[4]; bf16x8 v; } pf;
          if (hi == 0) { pf.u[0] = W[4 * t]; pf.u[1] = W[4 * t + 1]; pf.u[2] = r0; pf.u[3] = r1; }
          else         { pf.u[0] = r0; pf.u[1] = r1; pf.u[2] = W[4 * t + 2]; pf.u[3] = W[4 * t + 3]; }
#pragma unroll
          for (int mt = 0; mt < 4; mt++) {
            const bf16x8 vf = *(const bf16x8*)(vbuf + (mt * 32 + ql) * 40 + 16 * t + 8 * hi);
            acc[mt] = __builtin_amdgcn_mfma_f32_32x32x16_bf16(vf, pf.v, acc[mt], 0, 0, 0);
          }
        }
      }
      if (more) {
        *(f32x4*)(&lK[cur ^ 1][kdst]) = kr;
        *(f32x4*)(&lV[cur ^ 1][vdst]) = vr;
      }
      __syncthreads();
    }

    const float inv = 1.f / lsum;
    const int s_glob = qw0 + ql;
    unsigned short* op = O + ((size_t)(b * S + s_glob) * H + h) * DH;
#pragma unroll
    for (int mt = 0; mt < 4; mt++)
#pragma unroll
      for (int g = 0; g < 4; g++) {
        u16x4 ov;
#pragma unroll
        for (int jj = 0; jj < 4; jj++) ov[jj] = f2bf(acc[mt][4 * g + jj] * inv);
        *(u16x4*)(op + mt * 32 + 8 * g + 4 * hi) = ov;
      }
  }
}

extern "C" void kernel_launch(void* const* d_in, const int* in_sizes, int n_in,
                              void* d_out, int out_size, void* d_ws, size_t ws_size,
                              hipStream_t stream) {
  const float* x    = (const float*)d_in[0];
  const float* cosT = (const float*)d_in[1];
  const float* sinT = (const float*)d_in[2];
  const float* Wqkv = (const float*)d_in[3];
  const float* bqkv = (const float*)d_in[4];
  const float* Wout = (const float*)d_in[5];
  const float* bout = (const float*)d_in[6];

  char* ws = (char*)d_ws;
  unsigned short* xbf   = (unsigned short*)(ws);
  unsigned short* WqkvT = (unsigned short*)(ws + ((size_t)32 << 20));
  unsigned short* WoutT = (unsigned short*)(ws + ((size_t)56 << 20));
  unsigned short* VTb   = (unsigned short*)(ws + ((size_t)64 << 20));
  unsigned short* Qb = (unsigned short*)d_out;
  unsigned short* Kb = (unsigned short*)d_out + (size_t)M * D;
  unsigned short* Ob = xbf;

  cvt_kernel<<<M * D / 1024, 256, 0, stream>>>(x, xbf);
  transpose_kernel<<<dim3(N3 / 32, D / 32), dim3(32, 8), 0, stream>>>(Wqkv, WqkvT, D, N3);
  transpose_kernel<<<dim3(D / 32, D / 32), dim3(32, 8), 0, stream>>>(Wout, WoutT, D, D);
  gemm_bt<0><<<dim3((M / 256) * (N3 / 128)), 512, 0, stream>>>(xbf, WqkvT, bqkv, nullptr,
                                                               Qb, Kb, VTb, N3, N3 / 128);
  rope_kernel<<<(B * H * S * 16) / 256, 256, 0, stream>>>(Qb, cosT, sinT);
  rope_kernel<<<(B * H * S * 16) / 256, 256, 0, stream>>>(Kb, cosT, sinT);
  attn3_kernel<<<B * H * 4, 512, 0, stream>>>(Qb, Kb, VTb, Ob);
  gemm_bt<1><<<dim3((M / 256) * (D / 128)), 512, 0, stream>>>(Ob, WoutT, bout, (float*)d_out,
                                                              nullptr, nullptr, nullptr, D, D / 128);
}

// Round 5
// 502.220 us; speedup vs baseline: 2.7968x; 1.0515x over previous
//
#include <hip/hip_runtime.h>
#include <hip/hip_bf16.h>
#include <math.h>

typedef __attribute__((ext_vector_type(8))) short bf16x8;
typedef __attribute__((ext_vector_type(4))) float f32x4;
typedef __attribute__((ext_vector_type(16))) float f32x16;
typedef __attribute__((ext_vector_type(8))) unsigned short u16x8;
typedef __attribute__((ext_vector_type(4))) unsigned short u16x4;

static constexpr int B = 4, S = 2048, D = 2048, H = 16, DH = 128;
static constexpr int N3 = 3 * D;   // 6144
static constexpr int M = B * S;    // 8192

__device__ __forceinline__ unsigned short f2bf(float f) {
  unsigned u = __float_as_uint(f);
  u += 0x7fffu + ((u >> 16) & 1u);
  return (unsigned short)(u >> 16);
}
__device__ __forceinline__ float bf2f(unsigned short b) {
  return __uint_as_float(((unsigned)b) << 16);
}

// ---------------- elementwise f32 -> bf16 convert (vectorized) ----------------
__global__ __launch_bounds__(256) void cvt_kernel(const float* __restrict__ in,
                                                  unsigned short* __restrict__ out) {
  size_t i = (size_t)blockIdx.x * 256 + threadIdx.x;
  f32x4 v = *(const f32x4*)(in + i * 4);
  u16x4 o;
  o[0] = f2bf(v[0]); o[1] = f2bf(v[1]); o[2] = f2bf(v[2]); o[3] = f2bf(v[3]);
  *(u16x4*)(out + i * 4) = o;
}

// ---------------- tiled transpose-convert: W (K,N) f32 -> WT (N,K) bf16 ----------------
__global__ __launch_bounds__(256) void transpose_kernel(const float* __restrict__ W,
                                                        unsigned short* __restrict__ WT,
                                                        int K, int N) {
  __shared__ float t[32][33];
  int tx = threadIdx.x, ty = threadIdx.y;
  int n0 = blockIdx.x * 32, k0 = blockIdx.y * 32;
#pragma unroll
  for (int i = 0; i < 4; i++)
    t[ty + i * 8][tx] = W[(size_t)(k0 + ty + i * 8) * N + n0 + tx];
  __syncthreads();
#pragma unroll
  for (int i = 0; i < 4; i++)
    WT[(size_t)(n0 + ty + i * 8) * K + k0 + tx] = f2bf(t[tx][ty + i * 8]);
}

// ---------------- async global->LDS helper ----------------
__device__ __forceinline__ void gload_lds(const void* g, void* l) {
  __builtin_amdgcn_global_load_lds((const __attribute__((address_space(1))) void*)g,
                                   (__attribute__((address_space(3))) void*)l, 16, 0, 0);
}

// ---------------- bf16 MFMA GEMM, 256x256 tile, 4-buffer ring pipeline --------------
// BM=BN=256, BK=32, 512 thr = 8 waves (2 wm x 4 wn), per-wave 128x64 output
// (8 m-frags x 4 n-frags, A-frag reuse 4x, B-frag reuse 8x).
// 4 LDS buffers of 32KB (A 16KB | B 16KB): compute tile kt from buf[kt&3], stage
// tile kt+3 into buf[(kt+3)&3] -- never the buffer being read. One vmcnt(8) per
// tile (kt+2,kt+3 in flight -> kt+1 landed). 2 phases/tile, 16 MFMA each.
// Granule swizzle c^=((row>>1)&3): pre-swizzled global source + same XOR on read.
template <int EPI>
__global__ __launch_bounds__(512, 1) void gemm_bt(
    const unsigned short* __restrict__ A, const unsigned short* __restrict__ Bt,
    const float* __restrict__ bias, float* __restrict__ Cf,
    unsigned short* __restrict__ Qp, unsigned short* __restrict__ Kp,
    unsigned short* __restrict__ VTp, int Nn, int nbn) {
  __shared__ __align__(16) unsigned short lds[4 * 16384];  // 128 KiB
  constexpr int NT = 64;  // K = 2048 / BK = 32
  const int tid = threadIdx.x;
  const int l = tid & 63;
  const int w = tid >> 6;
  const int lr = l >> 4, lc = l & 15;
  const int wm = w >> 2, wn = w & 3;

  // XCD-aware swizzle (nwg % 8 == 0), bm-major
  const int nwg = gridDim.x;
  const int cpx = nwg >> 3;
  const int wg = blockIdx.x;
  const int swz = (wg & 7) * cpx + (wg >> 3);
  const int bm = swz / nbn;
  const int bn = swz - bm * nbn;

  // staging: per thread 2 A-granules + 2 B-granules (16B) per tile
  const unsigned short* Asrc[2];
  const unsigned short* Bsrc[2];
  int ldA[2], ldB[2];
#pragma unroll
  for (int i = 0; i < 2; i++) {
    const int gi = i * 512 + tid;
    const int r = gi >> 2, c = gi & 3;
    const int cs = c ^ ((r >> 1) & 3);
    Asrc[i] = A + (size_t)(bm * 256 + r) * 2048 + cs * 8;
    ldA[i] = gi * 8;
    Bsrc[i] = Bt + (size_t)(bn * 256 + r) * 2048 + cs * 8;
    ldB[i] = 8192 + gi * 8;
  }

  f32x4 acc[8][4];
#pragma unroll
  for (int m = 0; m < 8; m++)
#pragma unroll
    for (int n = 0; n < 4; n++) acc[m][n] = (f32x4)0.f;

  // ds_read offsets (swizzled): A-frag mf at aoff + mf*512, B-frag nf at boff + nf*512
  const int swzr = (lr ^ ((lc >> 1) & 3)) * 8;
  const int aoff = (wm * 128 + lc) * 32 + swzr;
  const int boff = 8192 + (wn * 64 + lc) * 32 + swzr;

  // prologue: stage tiles 0,1,2
#pragma unroll
  for (int t = 0; t < 3; t++) {
    unsigned short* sb = lds + t * 16384;
    gload_lds(Asrc[0] + t * 32, sb + ldA[0]);
    gload_lds(Asrc[1] + t * 32, sb + ldA[1]);
    gload_lds(Bsrc[0] + t * 32, sb + ldB[0]);
    gload_lds(Bsrc[1] + t * 32, sb + ldB[1]);
  }
  __builtin_amdgcn_sched_barrier(0);
  asm volatile("s_waitcnt vmcnt(8)" ::: "memory");   // tile 0 landed
  __builtin_amdgcn_s_barrier();
  __builtin_amdgcn_sched_barrier(0);

  for (int kt = 0; kt < NT; kt++) {
    const unsigned short* buf = lds + (kt & 3) * 16384;
    unsigned short* sb = lds + ((kt + 3) & 3) * 16384;
    const bool stg = (kt + 3) < NT;
    const int ks = (kt + 3) * 32;
    // ---- phase 0: frags m0-3 x n0-3 ----
    bf16x8 a0[4], bb[4];
#pragma unroll
    for (int mf = 0; mf < 4; mf++) a0[mf] = *(const bf16x8*)(buf + aoff + mf * 512);
#pragma unroll
    for (int nf = 0; nf < 4; nf++) bb[nf] = *(const bf16x8*)(buf + boff + nf * 512);
    if (stg) { gload_lds(Asrc[0] + ks, sb + ldA[0]); gload_lds(Asrc[1] + ks, sb + ldA[1]); }
    __builtin_amdgcn_sched_barrier(0);
    __builtin_amdgcn_s_barrier();
    asm volatile("s_waitcnt lgkmcnt(0)" ::: "memory");
    __builtin_amdgcn_sched_barrier(0);
    __builtin_amdgcn_s_setprio(1);
#pragma unroll
    for (int m = 0; m < 4; m++)
#pragma unroll
      for (int n = 0; n < 4; n++)
        acc[m][n] = __builtin_amdgcn_mfma_f32_16x16x32_bf16(a0[m], bb[n], acc[m][n], 0, 0, 0);
    __builtin_amdgcn_s_setprio(0);
    __builtin_amdgcn_sched_barrier(0);
    __builtin_amdgcn_s_barrier();
    // ---- phase 1: frags m4-7 x n0-3 (B reused) ----
    bf16x8 a1[4];
#pragma unroll
    for (int mf = 0; mf < 4; mf++) a1[mf] = *(const bf16x8*)(buf + aoff + (mf + 4) * 512);
    if (stg) { gload_lds(Bsrc[0] + ks, sb + ldB[0]); gload_lds(Bsrc[1] + ks, sb + ldB[1]); }
    __builtin_amdgcn_sched_barrier(0);
    __builtin_amdgcn_s_barrier();
    asm volatile("s_waitcnt lgkmcnt(0)" ::: "memory");
    __builtin_amdgcn_sched_barrier(0);
    __builtin_amdgcn_s_setprio(1);
#pragma unroll
    for (int m = 0; m < 4; m++)
#pragma unroll
      for (int n = 0; n < 4; n++)
        acc[m + 4][n] = __builtin_amdgcn_mfma_f32_16x16x32_bf16(a1[m], bb[n], acc[m + 4][n], 0, 0, 0);
    __builtin_amdgcn_s_setprio(0);
    __builtin_amdgcn_sched_barrier(0);
    if (kt + 3 < NT)      asm volatile("s_waitcnt vmcnt(8)" ::: "memory");  // kt+1 landed
    else if (kt + 2 < NT) asm volatile("s_waitcnt vmcnt(4)" ::: "memory");
    else if (kt + 1 < NT) asm volatile("s_waitcnt vmcnt(0)" ::: "memory");
    __builtin_amdgcn_sched_barrier(0);
    __builtin_amdgcn_s_barrier();
    __builtin_amdgcn_sched_barrier(0);
  }

#pragma unroll
  for (int m = 0; m < 8; m++) {
#pragma unroll
    for (int n = 0; n < 4; n++) {
      const int col = bn * 256 + wn * 64 + n * 16 + lc;
      const float bv = bias[col];
#pragma unroll
      for (int r = 0; r < 4; r++) {
        const int row = bm * 256 + wm * 128 + m * 16 + lr * 4 + r;
        const float v = acc[m][n][r] + bv;
        if (EPI == 0) {
          const unsigned short ob = f2bf(v);
          const int b = row >> 11, s = row & 2047;
          const int which = col >> 11, within = col & 2047;
          const int h = within >> 7, d = within & 127;
          const size_t bh = (size_t)(b * H + h);
          if (which == 0)      Qp[(bh * S + s) * DH + d] = ob;
          else if (which == 1) Kp[(bh * S + s) * DH + d] = ob;
          else                 VTp[(bh * DH + d) * S + s] = ob;
        } else {
          Cf[(size_t)row * Nn + col] = v;
        }
      }
    }
  }
}

// ---------------- RoPE in-place on (BH, S, DH) bf16, interleaved pairs ----------------
__global__ __launch_bounds__(256) void rope_kernel(unsigned short* __restrict__ T,
                                                   const float* __restrict__ cosT,
                                                   const float* __restrict__ sinT) {
  int t = blockIdx.x * 256 + threadIdx.x;
  int d8 = t & 15;
  int s = (t >> 4) & (S - 1);
  size_t off = (size_t)t * 8;
  u16x8 v = *(const u16x8*)(T + off);
  f32x4 c = *(const f32x4*)(cosT + (size_t)s * (DH / 2) + d8 * 4);
  f32x4 sn = *(const f32x4*)(sinT + (size_t)s * (DH / 2) + d8 * 4);
  u16x8 o;
#pragma unroll
  for (int j = 0; j < 4; j++) {
    float x1 = bf2f(v[2 * j]), x2 = bf2f(v[2 * j + 1]);
    o[2 * j]     = f2bf(x1 * c[j] - x2 * sn[j]);
    o[2 * j + 1] = f2bf(x1 * sn[j] + x2 * c[j]);
  }
  *(u16x8*)(T + off) = o;
}

// ---------------- flash attention v3: LDS-shared K/V tiles across 8 waves ----------
__global__ __launch_bounds__(512, 1) void attn3_kernel(
    const unsigned short* __restrict__ Q, const unsigned short* __restrict__ Kt,
    const unsigned short* __restrict__ VT, unsigned short* __restrict__ O) {
  __shared__ __align__(16) unsigned short lK[2][32 * 128];
  __shared__ __align__(16) unsigned short lV[2][128 * 40];
  const int tid = threadIdx.x;
  const int w = tid >> 6;       // wave 0..7
  const int l = tid & 63;
  const int ql = l & 31;
  const int hi = l >> 5;        // 0/1
  const int j = blockIdx.x;
  const int bh = ((j >> 3) & 7) * 8 + (j & 7);
  const int pr = j >> 6;                        // 0..3
  const int b = bh >> 4, h = bh & 15;
  const size_t base = (size_t)bh * S * DH;
  const float cl = 0.088388347648318447f * 1.44269504088896341f;  // (1/sqrt(DH))*log2e

  const int kdst = (tid * 8) ^ (((tid >> 4) & 7) << 3);
  const unsigned short* Kgb = Kt + base;
  const int vdh = tid >> 2;
  const int vc = (tid & 3) * 8;
  const int vdst = vdh * 40 + vc;
  const unsigned short* Vgr = VT + ((size_t)bh * DH + vdh) * S;
  const int sfix = (ql & 7) << 3;

  for (int half = 0; half < 2; half++) {
    const int strip = half ? 7 - pr : pr;
    const int qw0 = strip * 256 + w * 32;

    bf16x8 qf[8];
    const unsigned short* qp = Q + base + (size_t)(qw0 + ql) * DH + hi * 8;
#pragma unroll
    for (int t = 0; t < 8; t++) qf[t] = *(const bf16x8*)(qp + t * 16);

    f32x16 acc[4];
#pragma unroll
    for (int mt = 0; mt < 4; mt++) acc[mt] = (f32x16)0.f;
    float m = -INFINITY, lsum = 0.f;

    const int ntb = 8 * (strip + 1);
    const int last = 8 * strip + w;

    {
      f32x4 kr = *(const f32x4*)(Kgb + tid * 8);
      f32x4 vr = *(const f32x4*)(Vgr + vc);
      *(f32x4*)(&lK[0][kdst]) = kr;
      *(f32x4*)(&lV[0][vdst]) = vr;
      __syncthreads();
    }

    for (int kb = 0; kb < ntb; kb++) {
      const int cur = kb & 1;
      const bool more = (kb + 1 < ntb);
      f32x4 kr, vr;
      if (more) {
        kr = *(const f32x4*)(Kgb + (size_t)(kb + 1) * 4096 + tid * 8);
        vr = *(const f32x4*)(Vgr + (kb + 1) * 32 + vc);
      }
      if (kb <= last) {
        const unsigned short* kbuf = lK[cur];
        const unsigned short* vbuf = lV[cur];
        f32x16 st0 = (f32x16)0.f, st1 = (f32x16)0.f;
#pragma unroll
        for (int t = 0; t < 4; t++) {
          bf16x8 k0 = *(const bf16x8*)(kbuf + ((ql * 128 + (2 * t) * 16 + 8 * hi) ^ sfix));
          bf16x8 k1 = *(const bf16x8*)(kbuf + ((ql * 128 + (2 * t + 1) * 16 + 8 * hi) ^ sfix));
          st0 = __builtin_amdgcn_mfma_f32_32x32x16_bf16(k0, qf[2 * t], st0, 0, 0, 0);
          st1 = __builtin_amdgcn_mfma_f32_32x32x16_bf16(k1, qf[2 * t + 1], st1, 0, 0, 0);
        }
        float sv[16];
#pragma unroll
        for (int r = 0; r < 16; r++) sv[r] = st0[r] + st1[r];
        if (kb == last) {
#pragma unroll
          for (int r = 0; r < 16; r++) {
            const int klocal = (r & 3) + 8 * (r >> 2) + 4 * hi;
            sv[r] = (klocal > ql) ? -INFINITY : sv[r];
          }
        }
        float smax = sv[0];
#pragma unroll
        for (int r = 1; r < 16; r++) smax = fmaxf(smax, sv[r]);
        smax = fmaxf(smax, __shfl_xor(smax, 32));

        float fr = 1.f;
        if (!__all((smax - m) * cl <= 8.0f)) {
          const float mn = fmaxf(m, smax);
          fr = exp2f((m - mn) * cl);
          m = mn;
#pragma unroll
          for (int mt = 0; mt < 4; mt++)
#pragma unroll
            for (int r = 0; r < 16; r++) acc[mt][r] *= fr;
        }
        float p[16];
        float ps = 0.f;
#pragma unroll
        for (int r = 0; r < 16; r++) {
          p[r] = exp2f((sv[r] - m) * cl);
          ps += p[r];
        }
        lsum = lsum * fr + ps + __shfl_xor(ps, 32);

        unsigned W[8];
#pragma unroll
        for (int qd = 0; qd < 4; qd++) {
          W[2 * qd]     = (unsigned)f2bf(p[4 * qd])     | ((unsigned)f2bf(p[4 * qd + 1]) << 16);
          W[2 * qd + 1] = (unsigned)f2bf(p[4 * qd + 2]) | ((unsigned)f2bf(p[4 * qd + 3]) << 16);
        }
#pragma unroll
        for (int t = 0; t < 2; t++) {
          const unsigned s0 = hi ? W[4 * t] : W[4 * t + 2];
          const unsigned s1 = hi ? W[4 * t + 1] : W[4 * t + 3];
          const unsigned r0 = __shfl_xor((int)s0, 32);
          const unsigned r1 = __shfl_xor((int)s1, 32);
          union { unsigned u[4]; bf16x8 v; } pf;
          if (hi == 0) { pf.u[0] = W[4 * t]; pf.u[1] = W[4 * t + 1]; pf.u[2] = r0; pf.u[3] = r1; }
          else         { pf.u[0] = r0; pf.u[1] = r1; pf.u[2] = W[4 * t + 2]; pf.u[3] = W[4 * t + 3]; }
#pragma unroll
          for (int mt = 0; mt < 4; mt++) {
            const bf16x8 vf = *(const bf16x8*)(vbuf + (mt * 32 + ql) * 40 + 16 * t + 8 * hi);
            acc[mt] = __builtin_amdgcn_mfma_f32_32x32x16_bf16(vf, pf.v, acc[mt], 0, 0, 0);
          }
        }
      }
      if (more) {
        *(f32x4*)(&lK[cur ^ 1][kdst]) = kr;
        *(f32x4*)(&lV[cur ^ 1][vdst]) = vr;
      }
      __syncthreads();
    }

    const float inv = 1.f / lsum;
    const int s_glob = qw0 + ql;
    unsigned short* op = O + ((size_t)(b * S + s_glob) * H + h) * DH;
#pragma unroll
    for (int mt = 0; mt < 4; mt++)
#pragma unroll
      for (int g = 0; g < 4; g++) {
        u16x4 ov;
#pragma unroll
        for (int jj = 0; jj < 4; jj++) ov[jj] = f2bf(acc[mt][4 * g + jj] * inv);
        *(u16x4*)(op + mt * 32 + 8 * g + 4 * hi) = ov;
      }
  }
}

extern "C" void kernel_launch(void* const* d_in, const int* in_sizes, int n_in,
                              void* d_out, int out_size, void* d_ws, size_t ws_size,
                              hipStream_t stream) {
  const float* x    = (const float*)d_in[0];
  const float* cosT = (const float*)d_in[1];
  const float* sinT = (const float*)d_in[2];
  const float* Wqkv = (const float*)d_in[3];
  const float* bqkv = (const float*)d_in[4];
  const float* Wout = (const float*)d_in[5];
  const float* bout = (const float*)d_in[6];

  char* ws = (char*)d_ws;
  unsigned short* xbf   = (unsigned short*)(ws);
  unsigned short* WqkvT = (unsigned short*)(ws + ((size_t)32 << 20));
  unsigned short* WoutT = (unsigned short*)(ws + ((size_t)56 << 20));
  unsigned short* VTb   = (unsigned short*)(ws + ((size_t)64 << 20));
  unsigned short* Qb = (unsigned short*)d_out;
  unsigned short* Kb = (unsigned short*)d_out + (size_t)M * D;
  unsigned short* Ob = xbf;

  cvt_kernel<<<M * D / 1024, 256, 0, stream>>>(x, xbf);
  transpose_kernel<<<dim3(N3 / 32, D / 32), dim3(32, 8), 0, stream>>>(Wqkv, WqkvT, D, N3);
  transpose_kernel<<<dim3(D / 32, D / 32), dim3(32, 8), 0, stream>>>(Wout, WoutT, D, D);
  gemm_bt<0><<<dim3((M / 256) * (N3 / 256)), 512, 0, stream>>>(xbf, WqkvT, bqkv, nullptr,
                                                               Qb, Kb, VTb, N3, N3 / 256);
  rope_kernel<<<(B * H * S * 16) / 256, 256, 0, stream>>>(Qb, cosT, sinT);
  rope_kernel<<<(B * H * S * 16) / 256, 256, 0, stream>>>(Kb, cosT, sinT);
  attn3_kernel<<<B * H * 4, 512, 0, stream>>>(Qb, Kb, VTb, Ob);
  gemm_bt<1><<<dim3((M / 256) * (D / 256)), 512, 0, stream>>>(Ob, WoutT, bout, (float*)d_out,
                                                              nullptr, nullptr, nullptr, D, D / 256);
}

// Round 6
// 490.038 us; speedup vs baseline: 2.8663x; 1.0249x over previous
//
#include <hip/hip_runtime.h>
#include <hip/hip_bf16.h>
#include <math.h>

typedef __attribute__((ext_vector_type(8))) short bf16x8;
typedef __attribute__((ext_vector_type(4))) float f32x4;
typedef __attribute__((ext_vector_type(16))) float f32x16;
typedef __attribute__((ext_vector_type(8))) unsigned short u16x8;
typedef __attribute__((ext_vector_type(4))) unsigned short u16x4;

static constexpr int B = 4, S = 2048, D = 2048, H = 16, DH = 128;
static constexpr int N3 = 3 * D;   // 6144
static constexpr int M = B * S;    // 8192

__device__ __forceinline__ unsigned short f2bf(float f) {
  unsigned u = __float_as_uint(f);
  u += 0x7fffu + ((u >> 16) & 1u);
  return (unsigned short)(u >> 16);
}
__device__ __forceinline__ float bf2f(unsigned short b) {
  return __uint_as_float(((unsigned)b) << 16);
}

// ---------------- elementwise f32 -> bf16 convert (vectorized) ----------------
__global__ __launch_bounds__(256) void cvt_kernel(const float* __restrict__ in,
                                                  unsigned short* __restrict__ out) {
  size_t i = (size_t)blockIdx.x * 256 + threadIdx.x;
  f32x4 v = *(const f32x4*)(in + i * 4);
  u16x4 o;
  o[0] = f2bf(v[0]); o[1] = f2bf(v[1]); o[2] = f2bf(v[2]); o[3] = f2bf(v[3]);
  *(u16x4*)(out + i * 4) = o;
}

// ---------------- tiled transpose-convert: W (K,N) f32 -> WT (N,K) bf16 ----------------
__global__ __launch_bounds__(256) void transpose_kernel(const float* __restrict__ W,
                                                        unsigned short* __restrict__ WT,
                                                        int K, int N) {
  __shared__ float t[32][33];
  int tx = threadIdx.x, ty = threadIdx.y;
  int n0 = blockIdx.x * 32, k0 = blockIdx.y * 32;
#pragma unroll
  for (int i = 0; i < 4; i++)
    t[ty + i * 8][tx] = W[(size_t)(k0 + ty + i * 8) * N + n0 + tx];
  __syncthreads();
#pragma unroll
  for (int i = 0; i < 4; i++)
    WT[(size_t)(n0 + ty + i * 8) * K + k0 + tx] = f2bf(t[tx][ty + i * 8]);
}

// ---------------- async global->LDS helper ----------------
__device__ __forceinline__ void gload_lds(const void* g, void* l) {
  __builtin_amdgcn_global_load_lds((const __attribute__((address_space(1))) void*)g,
                                   (__attribute__((address_space(3))) void*)l, 16, 0, 0);
}

// ---------------- pipelined tile body: frag double-buffer, counted lgkm/vmcnt ---------
// Per tile kt: issue next tile's frag ds_reads (8 at top, 4 mid) into the OTHER regset;
// stage tile kt+3 (A at top, B mid); lgkmcnt(12) gates current frags (in-order LDS
// retirement); 2x16 MFMA clusters overlap the next-tile ds_read drain; one barrier.
template <bool NXT, bool STG, int VMN>
__device__ __forceinline__ void gemm_tile(
    const unsigned short* __restrict__ rb, unsigned short* __restrict__ sb,
    bf16x8 (&CA)[8], bf16x8 (&CB)[4], bf16x8 (&NA)[8], bf16x8 (&NB)[4],
    f32x4 (&acc)[8][4], int aoff, int boff,
    const unsigned short*& pA0, const unsigned short*& pA1,
    const unsigned short*& pB0, const unsigned short*& pB1,
    int ldA0, int ldA1, int ldB0, int ldB1) {
  if (NXT) {
#pragma unroll
    for (int mf = 0; mf < 4; mf++) NA[mf] = *(const bf16x8*)(rb + aoff + mf * 512);
#pragma unroll
    for (int nf = 0; nf < 4; nf++) NB[nf] = *(const bf16x8*)(rb + boff + nf * 512);
  }
  if (STG) { gload_lds(pA0, sb + ldA0); gload_lds(pA1, sb + ldA1); pA0 += 32; pA1 += 32; }
  __builtin_amdgcn_sched_barrier(0);
  if (NXT) asm volatile("s_waitcnt lgkmcnt(12)" ::: "memory");
  else     asm volatile("s_waitcnt lgkmcnt(4)" ::: "memory");
  __builtin_amdgcn_sched_barrier(0);
  __builtin_amdgcn_s_setprio(1);
#pragma unroll
  for (int m = 0; m < 4; m++)
#pragma unroll
    for (int n = 0; n < 4; n++)
      acc[m][n] = __builtin_amdgcn_mfma_f32_16x16x32_bf16(CA[m], CB[n], acc[m][n], 0, 0, 0);
  __builtin_amdgcn_s_setprio(0);
  __builtin_amdgcn_sched_barrier(0);
  if (NXT) {
#pragma unroll
    for (int mf = 4; mf < 8; mf++) NA[mf] = *(const bf16x8*)(rb + aoff + mf * 512);
  }
  if (STG) { gload_lds(pB0, sb + ldB0); gload_lds(pB1, sb + ldB1); pB0 += 32; pB1 += 32; }
  __builtin_amdgcn_sched_barrier(0);
  if (NXT) asm volatile("s_waitcnt lgkmcnt(12)" ::: "memory");
  else     asm volatile("s_waitcnt lgkmcnt(0)" ::: "memory");
  __builtin_amdgcn_sched_barrier(0);
  __builtin_amdgcn_s_setprio(1);
#pragma unroll
  for (int m = 0; m < 4; m++)
#pragma unroll
    for (int n = 0; n < 4; n++)
      acc[m + 4][n] = __builtin_amdgcn_mfma_f32_16x16x32_bf16(CA[m + 4], CB[n], acc[m + 4][n], 0, 0, 0);
  __builtin_amdgcn_s_setprio(0);
  __builtin_amdgcn_sched_barrier(0);
  if (VMN == 4) {
    asm volatile("s_waitcnt vmcnt(4)" ::: "memory");
    __builtin_amdgcn_s_barrier();
  } else if (VMN == 0) {
    asm volatile("s_waitcnt vmcnt(0)" ::: "memory");
    __builtin_amdgcn_s_barrier();
  }
  __builtin_amdgcn_sched_barrier(0);
}

// ---------------- bf16 MFMA GEMM, 256x256 tile, 4-buffer ring, frag dbuf --------------
template <int EPI>
__global__ __launch_bounds__(512, 1) void gemm_bt(
    const unsigned short* __restrict__ A, const unsigned short* __restrict__ Bt,
    const float* __restrict__ bias, float* __restrict__ Cf,
    unsigned short* __restrict__ Qp, unsigned short* __restrict__ Kp,
    unsigned short* __restrict__ VTp, int Nn, int nbn) {
  __shared__ __align__(16) unsigned short lds[4 * 16384];  // 128 KiB
  constexpr int NT = 64;  // K = 2048 / BK = 32
  const int tid = threadIdx.x;
  const int l = tid & 63;
  const int w = tid >> 6;
  const int lr = l >> 4, lc = l & 15;
  const int wm = w >> 2, wn = w & 3;

  // XCD-aware swizzle (nwg % 8 == 0), bm-major
  const int nwg = gridDim.x;
  const int cpx = nwg >> 3;
  const int wg = blockIdx.x;
  const int swz = (wg & 7) * cpx + (wg >> 3);
  const int bm = swz / nbn;
  const int bn = swz - bm * nbn;

  // staging: per thread 2 A-granules + 2 B-granules (16B) per tile, pre-swizzled source
  const int gi0 = tid, gi1 = 512 + tid;
  const int r0 = gi0 >> 2, c0 = (gi0 & 3) ^ ((r0 >> 1) & 3);
  const int r1 = gi1 >> 2, c1 = (gi1 & 3) ^ ((r1 >> 1) & 3);
  const unsigned short* pA0 = A + (size_t)(bm * 256 + r0) * 2048 + c0 * 8;
  const unsigned short* pA1 = A + (size_t)(bm * 256 + r1) * 2048 + c1 * 8;
  const unsigned short* pB0 = Bt + (size_t)(bn * 256 + r0) * 2048 + c0 * 8;
  const unsigned short* pB1 = Bt + (size_t)(bn * 256 + r1) * 2048 + c1 * 8;
  const int ldA0 = gi0 * 8, ldA1 = gi1 * 8;
  const int ldB0 = 8192 + gi0 * 8, ldB1 = 8192 + gi1 * 8;

  f32x4 acc[8][4];
#pragma unroll
  for (int m = 0; m < 8; m++)
#pragma unroll
    for (int n = 0; n < 4; n++) acc[m][n] = (f32x4)0.f;

  // ds_read offsets (swizzled)
  const int swzr = (lr ^ ((lc >> 1) & 3)) * 8;
  const int aoff = (wm * 128 + lc) * 32 + swzr;
  const int boff = 8192 + (wn * 64 + lc) * 32 + swzr;

  // prologue: stage tiles 0,1,2
#pragma unroll
  for (int t = 0; t < 3; t++) {
    unsigned short* sb = lds + t * 16384;
    gload_lds(pA0, sb + ldA0); gload_lds(pA1, sb + ldA1);
    gload_lds(pB0, sb + ldB0); gload_lds(pB1, sb + ldB1);
    pA0 += 32; pA1 += 32; pB0 += 32; pB1 += 32;
  }
  __builtin_amdgcn_sched_barrier(0);
  asm volatile("s_waitcnt vmcnt(4)" ::: "memory");  // tiles 0,1 landed
  __builtin_amdgcn_s_barrier();
  __builtin_amdgcn_sched_barrier(0);

  bf16x8 a0[8], b0[4], a1[8], b1[4];
#pragma unroll
  for (int mf = 0; mf < 4; mf++) a0[mf] = *(const bf16x8*)(lds + aoff + mf * 512);
#pragma unroll
  for (int nf = 0; nf < 4; nf++) b0[nf] = *(const bf16x8*)(lds + boff + nf * 512);
#pragma unroll
  for (int mf = 4; mf < 8; mf++) a0[mf] = *(const bf16x8*)(lds + aoff + mf * 512);
  __builtin_amdgcn_sched_barrier(0);

  for (int kt = 0; kt < 60; kt += 2) {
    gemm_tile<true, true, 4>(lds + ((kt + 1) & 3) * 16384, lds + ((kt + 3) & 3) * 16384,
                             a0, b0, a1, b1, acc, aoff, boff,
                             pA0, pA1, pB0, pB1, ldA0, ldA1, ldB0, ldB1);
    gemm_tile<true, true, 4>(lds + ((kt + 2) & 3) * 16384, lds + ((kt + 4) & 3) * 16384,
                             a1, b1, a0, b0, acc, aoff, boff,
                             pA0, pA1, pB0, pB1, ldA0, ldA1, ldB0, ldB1);
  }
  gemm_tile<true, true, 4>(lds + (61 & 3) * 16384, lds + (63 & 3) * 16384,   // kt=60
                           a0, b0, a1, b1, acc, aoff, boff,
                           pA0, pA1, pB0, pB1, ldA0, ldA1, ldB0, ldB1);
  gemm_tile<true, false, 0>(lds + (62 & 3) * 16384, lds,                     // kt=61
                            a1, b1, a0, b0, acc, aoff, boff,
                            pA0, pA1, pB0, pB1, ldA0, ldA1, ldB0, ldB1);
  gemm_tile<true, false, -1>(lds + (63 & 3) * 16384, lds,                    // kt=62
                             a0, b0, a1, b1, acc, aoff, boff,
                             pA0, pA1, pB0, pB1, ldA0, ldA1, ldB0, ldB1);
  gemm_tile<false, false, -1>(lds, lds,                                      // kt=63
                              a1, b1, a0, b0, acc, aoff, boff,
                              pA0, pA1, pB0, pB1, ldA0, ldA1, ldB0, ldB1);

#pragma unroll
  for (int m = 0; m < 8; m++) {
#pragma unroll
    for (int n = 0; n < 4; n++) {
      const int col = bn * 256 + wn * 64 + n * 16 + lc;
      const float bv = bias[col];
#pragma unroll
      for (int r = 0; r < 4; r++) {
        const int row = bm * 256 + wm * 128 + m * 16 + lr * 4 + r;
        const float v = acc[m][n][r] + bv;
        if (EPI == 0) {
          const unsigned short ob = f2bf(v);
          const int b = row >> 11, s = row & 2047;
          const int which = col >> 11, within = col & 2047;
          const int h = within >> 7, d = within & 127;
          const size_t bh = (size_t)(b * H + h);
          if (which == 0)      Qp[(bh * S + s) * DH + d] = ob;
          else if (which == 1) Kp[(bh * S + s) * DH + d] = ob;
          else                 VTp[(bh * DH + d) * S + s] = ob;
        } else {
          Cf[(size_t)row * Nn + col] = v;
        }
      }
    }
  }
}

// ---------------- RoPE in-place on (BH, S, DH) bf16, interleaved pairs ----------------
__global__ __launch_bounds__(256) void rope_kernel(unsigned short* __restrict__ T,
                                                   const float* __restrict__ cosT,
                                                   const float* __restrict__ sinT) {
  int t = blockIdx.x * 256 + threadIdx.x;
  int d8 = t & 15;
  int s = (t >> 4) & (S - 1);
  size_t off = (size_t)t * 8;
  u16x8 v = *(const u16x8*)(T + off);
  f32x4 c = *(const f32x4*)(cosT + (size_t)s * (DH / 2) + d8 * 4);
  f32x4 sn = *(const f32x4*)(sinT + (size_t)s * (DH / 2) + d8 * 4);
  u16x8 o;
#pragma unroll
  for (int j = 0; j < 4; j++) {
    float x1 = bf2f(v[2 * j]), x2 = bf2f(v[2 * j + 1]);
    o[2 * j]     = f2bf(x1 * c[j] - x2 * sn[j]);
    o[2 * j + 1] = f2bf(x1 * sn[j] + x2 * c[j]);
  }
  *(u16x8*)(T + off) = o;
}

// ---------------- flash attention v3: LDS-shared K/V tiles across 8 waves ----------
__global__ __launch_bounds__(512, 1) void attn3_kernel(
    const unsigned short* __restrict__ Q, const unsigned short* __restrict__ Kt,
    const unsigned short* __restrict__ VT, unsigned short* __restrict__ O) {
  __shared__ __align__(16) unsigned short lK[2][32 * 128];
  __shared__ __align__(16) unsigned short lV[2][128 * 40];
  const int tid = threadIdx.x;
  const int w = tid >> 6;       // wave 0..7
  const int l = tid & 63;
  const int ql = l & 31;
  const int hi = l >> 5;        // 0/1
  const int j = blockIdx.x;
  const int bh = ((j >> 3) & 7) * 8 + (j & 7);
  const int pr = j >> 6;                        // 0..3
  const int b = bh >> 4, h = bh & 15;
  const size_t base = (size_t)bh * S * DH;
  const float cl = 0.088388347648318447f * 1.44269504088896341f;  // (1/sqrt(DH))*log2e

  const int kdst = (tid * 8) ^ (((tid >> 4) & 7) << 3);
  const unsigned short* Kgb = Kt + base;
  const int vdh = tid >> 2;
  const int vc = (tid & 3) * 8;
  const int vdst = vdh * 40 + vc;
  const unsigned short* Vgr = VT + ((size_t)bh * DH + vdh) * S;
  const int sfix = (ql & 7) << 3;

  for (int half = 0; half < 2; half++) {
    const int strip = half ? 7 - pr : pr;
    const int qw0 = strip * 256 + w * 32;

    bf16x8 qf[8];
    const unsigned short* qp = Q + base + (size_t)(qw0 + ql) * DH + hi * 8;
#pragma unroll
    for (int t = 0; t < 8; t++) qf[t] = *(const bf16x8*)(qp + t * 16);

    f32x16 acc[4];
#pragma unroll
    for (int mt = 0; mt < 4; mt++) acc[mt] = (f32x16)0.f;
    float m = -INFINITY, lsum = 0.f;

    const int ntb = 8 * (strip + 1);
    const int last = 8 * strip + w;

    {
      f32x4 kr = *(const f32x4*)(Kgb + tid * 8);
      f32x4 vr = *(const f32x4*)(Vgr + vc);
      *(f32x4*)(&lK[0][kdst]) = kr;
      *(f32x4*)(&lV[0][vdst]) = vr;
      __syncthreads();
    }

    for (int kb = 0; kb < ntb; kb++) {
      const int cur = kb & 1;
      const bool more = (kb + 1 < ntb);
      f32x4 kr, vr;
      if (more) {
        kr = *(const f32x4*)(Kgb + (size_t)(kb + 1) * 4096 + tid * 8);
        vr = *(const f32x4*)(Vgr + (kb + 1) * 32 + vc);
      }
      if (kb <= last) {
        const unsigned short* kbuf = lK[cur];
        const unsigned short* vbuf = lV[cur];
        f32x16 st0 = (f32x16)0.f, st1 = (f32x16)0.f;
#pragma unroll
        for (int t = 0; t < 4; t++) {
          bf16x8 k0 = *(const bf16x8*)(kbuf + ((ql * 128 + (2 * t) * 16 + 8 * hi) ^ sfix));
          bf16x8 k1 = *(const bf16x8*)(kbuf + ((ql * 128 + (2 * t + 1) * 16 + 8 * hi) ^ sfix));
          st0 = __builtin_amdgcn_mfma_f32_32x32x16_bf16(k0, qf[2 * t], st0, 0, 0, 0);
          st1 = __builtin_amdgcn_mfma_f32_32x32x16_bf16(k1, qf[2 * t + 1], st1, 0, 0, 0);
        }
        float sv[16];
#pragma unroll
        for (int r = 0; r < 16; r++) sv[r] = st0[r] + st1[r];
        if (kb == last) {
#pragma unroll
          for (int r = 0; r < 16; r++) {
            const int klocal = (r & 3) + 8 * (r >> 2) + 4 * hi;
            sv[r] = (klocal > ql) ? -INFINITY : sv[r];
          }
        }
        float smax = sv[0];
#pragma unroll
        for (int r = 1; r < 16; r++) smax = fmaxf(smax, sv[r]);
        smax = fmaxf(smax, __shfl_xor(smax, 32));

        float fr = 1.f;
        if (!__all((smax - m) * cl <= 8.0f)) {
          const float mn = fmaxf(m, smax);
          fr = exp2f((m - mn) * cl);
          m = mn;
#pragma unroll
          for (int mt = 0; mt < 4; mt++)
#pragma unroll
            for (int r = 0; r < 16; r++) acc[mt][r] *= fr;
        }
        float p[16];
        float ps = 0.f;
#pragma unroll
        for (int r = 0; r < 16; r++) {
          p[r] = exp2f((sv[r] - m) * cl);
          ps += p[r];
        }
        lsum = lsum * fr + ps + __shfl_xor(ps, 32);

        unsigned W[8];
#pragma unroll
        for (int qd = 0; qd < 4; qd++) {
          W[2 * qd]     = (unsigned)f2bf(p[4 * qd])     | ((unsigned)f2bf(p[4 * qd + 1]) << 16);
          W[2 * qd + 1] = (unsigned)f2bf(p[4 * qd + 2]) | ((unsigned)f2bf(p[4 * qd + 3]) << 16);
        }
#pragma unroll
        for (int t = 0; t < 2; t++) {
          const unsigned s0 = hi ? W[4 * t] : W[4 * t + 2];
          const unsigned s1 = hi ? W[4 * t + 1] : W[4 * t + 3];
          const unsigned r0 = __shfl_xor((int)s0, 32);
          const unsigned r1 = __shfl_xor((int)s1, 32);
          union { unsigned u[4]; bf16x8 v; } pf;
          if (hi == 0) { pf.u[0] = W[4 * t]; pf.u[1] = W[4 * t + 1]; pf.u[2] = r0; pf.u[3] = r1; }
          else         { pf.u[0] = r0; pf.u[1] = r1; pf.u[2] = W[4 * t + 2]; pf.u[3] = W[4 * t + 3]; }
#pragma unroll
          for (int mt = 0; mt < 4; mt++) {
            const bf16x8 vf = *(const bf16x8*)(vbuf + (mt * 32 + ql) * 40 + 16 * t + 8 * hi);
            acc[mt] = __builtin_amdgcn_mfma_f32_32x32x16_bf16(vf, pf.v, acc[mt], 0, 0, 0);
          }
        }
      }
      if (more) {
        *(f32x4*)(&lK[cur ^ 1][kdst]) = kr;
        *(f32x4*)(&lV[cur ^ 1][vdst]) = vr;
      }
      __syncthreads();
    }

    const float inv = 1.f / lsum;
    const int s_glob = qw0 + ql;
    unsigned short* op = O + ((size_t)(b * S + s_glob) * H + h) * DH;
#pragma unroll
    for (int mt = 0; mt < 4; mt++)
#pragma unroll
      for (int g = 0; g < 4; g++) {
        u16x4 ov;
#pragma unroll
        for (int jj = 0; jj < 4; jj++) ov[jj] = f2bf(acc[mt][4 * g + jj] * inv);
        *(u16x4*)(op + mt * 32 + 8 * g + 4 * hi) = ov;
      }
  }
}

extern "C" void kernel_launch(void* const* d_in, const int* in_sizes, int n_in,
                              void* d_out, int out_size, void* d_ws, size_t ws_size,
                              hipStream_t stream) {
  const float* x    = (const float*)d_in[0];
  const float* cosT = (const float*)d_in[1];
  const float* sinT = (const float*)d_in[2];
  const float* Wqkv = (const float*)d_in[3];
  const float* bqkv = (const float*)d_in[4];
  const float* Wout = (const float*)d_in[5];
  const float* bout = (const float*)d_in[6];

  char* ws = (char*)d_ws;
  unsigned short* xbf   = (unsigned short*)(ws);
  unsigned short* WqkvT = (unsigned short*)(ws + ((size_t)32 << 20));
  unsigned short* WoutT = (unsigned short*)(ws + ((size_t)56 << 20));
  unsigned short* VTb   = (unsigned short*)(ws + ((size_t)64 << 20));
  unsigned short* Qb = (unsigned short*)d_out;
  unsigned short* Kb = (unsigned short*)d_out + (size_t)M * D;
  unsigned short* Ob = xbf;

  cvt_kernel<<<M * D / 1024, 256, 0, stream>>>(x, xbf);
  transpose_kernel<<<dim3(N3 / 32, D / 32), dim3(32, 8), 0, stream>>>(Wqkv, WqkvT, D, N3);
  transpose_kernel<<<dim3(D / 32, D / 32), dim3(32, 8), 0, stream>>>(Wout, WoutT, D, D);
  gemm_bt<0><<<dim3((M / 256) * (N3 / 256)), 512, 0, stream>>>(xbf, WqkvT, bqkv, nullptr,
                                                               Qb, Kb, VTb, N3, N3 / 256);
  rope_kernel<<<(B * H * S * 16) / 256, 256, 0, stream>>>(Qb, cosT, sinT);
  rope_kernel<<<(B * H * S * 16) / 256, 256, 0, stream>>>(Kb, cosT, sinT);
  attn3_kernel<<<B * H * 4, 512, 0, stream>>>(Qb, Kb, VTb, Ob);
  gemm_bt<1><<<dim3((M / 256) * (D / 256)), 512, 0, stream>>>(Ob, WoutT, bout, (float*)d_out,
                                                              nullptr, nullptr, nullptr, D, D / 256);
}

// Round 7
// 487.021 us; speedup vs baseline: 2.8840x; 1.0062x over previous
//
#include <hip/hip_runtime.h>
#include <hip/hip_bf16.h>
#include <math.h>

typedef __attribute__((ext_vector_type(8))) short bf16x8;
typedef __attribute__((ext_vector_type(4))) float f32x4;
typedef __attribute__((ext_vector_type(16))) float f32x16;
typedef __attribute__((ext_vector_type(8))) unsigned short u16x8;
typedef __attribute__((ext_vector_type(4))) unsigned short u16x4;

static constexpr int B = 4, S = 2048, D = 2048, H = 16, DH = 128;
static constexpr int N3 = 3 * D;   // 6144
static constexpr int M = B * S;    // 8192

__device__ __forceinline__ unsigned short f2bf(float f) {
  unsigned u = __float_as_uint(f);
  u += 0x7fffu + ((u >> 16) & 1u);
  return (unsigned short)(u >> 16);
}
__device__ __forceinline__ float bf2f(unsigned short b) {
  return __uint_as_float(((unsigned)b) << 16);
}

// ---------------- elementwise f32 -> bf16 convert (vectorized) ----------------
__global__ __launch_bounds__(256) void cvt_kernel(const float* __restrict__ in,
                                                  unsigned short* __restrict__ out) {
  size_t i = (size_t)blockIdx.x * 256 + threadIdx.x;
  f32x4 v = *(const f32x4*)(in + i * 4);
  u16x4 o;
  o[0] = f2bf(v[0]); o[1] = f2bf(v[1]); o[2] = f2bf(v[2]); o[3] = f2bf(v[3]);
  *(u16x4*)(out + i * 4) = o;
}

// ---------------- tiled transpose-convert: W (K,N) f32 -> WT (N,K) bf16 ----------------
__global__ __launch_bounds__(256) void transpose_kernel(const float* __restrict__ W,
                                                        unsigned short* __restrict__ WT,
                                                        int K, int N) {
  __shared__ float t[32][33];
  int tx = threadIdx.x, ty = threadIdx.y;
  int n0 = blockIdx.x * 32, k0 = blockIdx.y * 32;
#pragma unroll
  for (int i = 0; i < 4; i++)
    t[ty + i * 8][tx] = W[(size_t)(k0 + ty + i * 8) * N + n0 + tx];
  __syncthreads();
#pragma unroll
  for (int i = 0; i < 4; i++)
    WT[(size_t)(n0 + ty + i * 8) * K + k0 + tx] = f2bf(t[tx][ty + i * 8]);
}

// ---------------- async global->LDS helper ----------------
__device__ __forceinline__ void gload_lds(const void* g, void* l) {
  __builtin_amdgcn_global_load_lds((const __attribute__((address_space(1))) void*)g,
                                   (__attribute__((address_space(3))) void*)l, 16, 0, 0);
}

// ---------------- bf16 MFMA GEMM, 256x256 tile, m201-style 4-phase pipeline -----------
// BK=64, 2 LDS dbuf. LDS: A[db][half][kh][128][32] (64KB) + B same (64KB) = 128KB.
// 512 thr = 8 waves (2 wm x 4 wn), per-wave 128x64 output. 4 phases/tile = (kh,mh):
//   {4 A-frag (+4 B-frag if mh==0) ds_read_b128; 2 gload_lds staging tile t+1;
//    lgkm(0); 16 MFMA; vmcnt(4); s_barrier}
// Each wave stages exactly the chunks IT reads, one phase-aligned chunk per phase
// (A: rows mh*64+wn*16+[0,16) of half wm, kh-block kh; B: rows (wm*2+(wn&1))*32+
// mh*16+[0,16) of half wn>>1). 4-phase lead + per-phase vmcnt(4) proves reads safe;
// vmcnt never drains to 0 in the loop. Granule swizzle g^=(row>>1)&3 on stage source
// and ds_read (measured 0 conflicts).
template <int EPI>
__global__ __launch_bounds__(512, 1) void gemm_bt(
    const unsigned short* __restrict__ A, const unsigned short* __restrict__ Bt,
    const float* __restrict__ bias, float* __restrict__ Cf,
    unsigned short* __restrict__ Qp, unsigned short* __restrict__ Kp,
    unsigned short* __restrict__ VTp, int Nn, int nbn) {
  __shared__ __align__(16) unsigned short lds[65536];  // 128 KiB
  constexpr int NT = 32;  // K = 2048 / BK = 64
  const int tid = threadIdx.x;
  const int l = tid & 63;
  const int w = tid >> 6;
  const int lc = l & 15, lr = l >> 4;
  const int wm = w >> 2, wn = w & 3;

  // XCD-aware swizzle (nwg % 8 == 0), bm-major
  const int nwg = gridDim.x;
  const int cpx = nwg >> 3;
  const int wg = blockIdx.x;
  const int swz = (wg & 7) * cpx + (wg >> 3);
  const int bm = swz / nbn;
  const int bn = swz - bm * nbn;

  // ---- staging setup (per thread): 1 A-chunk + 1 B-chunk per phase ----
  const int lq = l >> 2, lg = l & 3;
  const int gsw = lg ^ ((l >> 3) & 3);  // pre-swizzled source granule
  const unsigned short* sA[2];
  const unsigned short* sB[2];
  int dA[2], dB[2];
#pragma unroll
  for (int mh = 0; mh < 2; mh++) {
    const int rowA = mh * 64 + wn * 16 + lq;               // row in A-half wm
    sA[mh] = A + (size_t)(bm * 256 + wm * 128 + rowA) * 2048 + gsw * 8;
    dA[mh] = wm * 8192 + rowA * 32 + lg * 8;               // + db*16384 + kh*4096
    const int rowB = (wm * 2 + (wn & 1)) * 32 + mh * 16 + lq;  // row in B-half wn>>1
    sB[mh] = Bt + (size_t)(bn * 256 + (wn >> 1) * 128 + rowB) * 2048 + gsw * 8;
    dB[mh] = 32768 + (wn >> 1) * 8192 + rowB * 32 + lg * 8;
  }

  // ---- fragment-read offsets (swizzled) ----
  const int rsw = (lr ^ ((lc >> 1) & 3)) * 8;
  const int frA = wm * 8192 + lc * 32 + rsw;               // + db*16384+kh*4096+mh*2048+mt*512
  const int frB = 32768 + (wn >> 1) * 8192 + ((wn & 1) * 64 + lc) * 32 + rsw;  // + nt*512

  f32x4 acc[8][4];
#pragma unroll
  for (int m = 0; m < 8; m++)
#pragma unroll
    for (int n = 0; n < 4; n++) acc[m][n] = (f32x4)0.f;

#define STG(t1, kh, mh)                                                          \
  do {                                                                           \
    const int dbo_ = ((t1) & 1) * 16384 + (kh) * 4096;                           \
    const int ko_ = (t1) * 64 + (kh) * 32;                                       \
    gload_lds(sA[mh] + ko_, lds + dbo_ + dA[mh]);                                \
    gload_lds(sB[mh] + ko_, lds + dbo_ + dB[mh]);                                \
  } while (0)

  // prologue: stage tile 0 fully, drain once, publish
  STG(0, 0, 0); STG(0, 0, 1); STG(0, 1, 0); STG(0, 1, 1);
  __builtin_amdgcn_sched_barrier(0);
  asm volatile("s_waitcnt vmcnt(0)" ::: "memory");
  __builtin_amdgcn_s_barrier();
  __builtin_amdgcn_sched_barrier(0);

  bf16x8 bfr[4];

#define PHASE(db, kh, mh, DOSTG, t1)                                             \
  do {                                                                           \
    bf16x8 af0, af1, af2, af3;                                                   \
    const int ab_ = (db) * 16384 + (kh) * 4096 + frA + (mh) * 2048;              \
    af0 = *(const bf16x8*)(lds + ab_);                                           \
    af1 = *(const bf16x8*)(lds + ab_ + 512);                                     \
    af2 = *(const bf16x8*)(lds + ab_ + 1024);                                    \
    af3 = *(const bf16x8*)(lds + ab_ + 1536);                                    \
    if (mh == 0) {                                                               \
      const int bb_ = (db) * 16384 + (kh) * 4096 + frB;                          \
      bfr[0] = *(const bf16x8*)(lds + bb_);                                      \
      bfr[1] = *(const bf16x8*)(lds + bb_ + 512);                                \
      bfr[2] = *(const bf16x8*)(lds + bb_ + 1024);                               \
      bfr[3] = *(const bf16x8*)(lds + bb_ + 1536);                               \
    }                                                                            \
    if (DOSTG) STG(t1, kh, mh);                                                  \
    __builtin_amdgcn_sched_barrier(0);                                           \
    asm volatile("s_waitcnt lgkmcnt(0)" ::: "memory");                           \
    __builtin_amdgcn_sched_barrier(0);                                           \
    __builtin_amdgcn_s_setprio(1);                                               \
    _Pragma("unroll")                                                            \
    for (int nt = 0; nt < 4; nt++) {                                             \
      acc[(mh)*4 + 0][nt] = __builtin_amdgcn_mfma_f32_16x16x32_bf16(af0, bfr[nt], acc[(mh)*4 + 0][nt], 0, 0, 0); \
      acc[(mh)*4 + 1][nt] = __builtin_amdgcn_mfma_f32_16x16x32_bf16(af1, bfr[nt], acc[(mh)*4 + 1][nt], 0, 0, 0); \
      acc[(mh)*4 + 2][nt] = __builtin_amdgcn_mfma_f32_16x16x32_bf16(af2, bfr[nt], acc[(mh)*4 + 2][nt], 0, 0, 0); \
      acc[(mh)*4 + 3][nt] = __builtin_amdgcn_mfma_f32_16x16x32_bf16(af3, bfr[nt], acc[(mh)*4 + 3][nt], 0, 0, 0); \
    }                                                                            \
    __builtin_amdgcn_s_setprio(0);                                               \
    __builtin_amdgcn_sched_barrier(0);                                           \
    asm volatile("s_waitcnt vmcnt(4)" ::: "memory");                             \
    __builtin_amdgcn_s_barrier();                                                \
    __builtin_amdgcn_sched_barrier(0);                                           \
  } while (0)

#pragma unroll 2
  for (int t = 0; t < NT; t++) {
    const int db = t & 1;
    const bool dg = (t + 1) < NT;
    PHASE(db, 0, 0, dg, t + 1);
    PHASE(db, 0, 1, dg, t + 1);
    PHASE(db, 1, 0, dg, t + 1);
    PHASE(db, 1, 1, dg, t + 1);
  }
#undef PHASE
#undef STG

#pragma unroll
  for (int m = 0; m < 8; m++) {
#pragma unroll
    for (int n = 0; n < 4; n++) {
      const int col = bn * 256 + wn * 64 + n * 16 + lc;
      const float bv = bias[col];
#pragma unroll
      for (int r = 0; r < 4; r++) {
        const int row = bm * 256 + wm * 128 + (m >> 2) * 64 + (m & 3) * 16 + lr * 4 + r;
        const float v = acc[m][n][r] + bv;
        if (EPI == 0) {
          const unsigned short ob = f2bf(v);
          const int b = row >> 11, s = row & 2047;
          const int which = col >> 11, within = col & 2047;
          const int h = within >> 7, d = within & 127;
          const size_t bh = (size_t)(b * H + h);
          if (which == 0)      Qp[(bh * S + s) * DH + d] = ob;
          else if (which == 1) Kp[(bh * S + s) * DH + d] = ob;
          else                 VTp[(bh * DH + d) * S + s] = ob;
        } else {
          Cf[(size_t)row * Nn + col] = v;
        }
      }
    }
  }
}

// ---------------- RoPE in-place on (BH, S, DH) bf16, interleaved pairs ----------------
__global__ __launch_bounds__(256) void rope_kernel(unsigned short* __restrict__ T,
                                                   const float* __restrict__ cosT,
                                                   const float* __restrict__ sinT) {
  int t = blockIdx.x * 256 + threadIdx.x;
  int d8 = t & 15;
  int s = (t >> 4) & (S - 1);
  size_t off = (size_t)t * 8;
  u16x8 v = *(const u16x8*)(T + off);
  f32x4 c = *(const f32x4*)(cosT + (size_t)s * (DH / 2) + d8 * 4);
  f32x4 sn = *(const f32x4*)(sinT + (size_t)s * (DH / 2) + d8 * 4);
  u16x8 o;
#pragma unroll
  for (int j = 0; j < 4; j++) {
    float x1 = bf2f(v[2 * j]), x2 = bf2f(v[2 * j + 1]);
    o[2 * j]     = f2bf(x1 * c[j] - x2 * sn[j]);
    o[2 * j + 1] = f2bf(x1 * sn[j] + x2 * c[j]);
  }
  *(u16x8*)(T + off) = o;
}

// ---------------- flash attention v3: LDS-shared K/V tiles across 8 waves ----------
__global__ __launch_bounds__(512, 1) void attn3_kernel(
    const unsigned short* __restrict__ Q, const unsigned short* __restrict__ Kt,
    const unsigned short* __restrict__ VT, unsigned short* __restrict__ O) {
  __shared__ __align__(16) unsigned short lK[2][32 * 128];
  __shared__ __align__(16) unsigned short lV[2][128 * 40];
  const int tid = threadIdx.x;
  const int w = tid >> 6;       // wave 0..7
  const int l = tid & 63;
  const int ql = l & 31;
  const int hi = l >> 5;        // 0/1
  const int j = blockIdx.x;
  const int bh = ((j >> 3) & 7) * 8 + (j & 7);
  const int pr = j >> 6;                        // 0..3
  const int b = bh >> 4, h = bh & 15;
  const size_t base = (size_t)bh * S * DH;
  const float cl = 0.088388347648318447f * 1.44269504088896341f;  // (1/sqrt(DH))*log2e

  const int kdst = (tid * 8) ^ (((tid >> 4) & 7) << 3);
  const unsigned short* Kgb = Kt + base;
  const int vdh = tid >> 2;
  const int vc = (tid & 3) * 8;
  const int vdst = vdh * 40 + vc;
  const unsigned short* Vgr = VT + ((size_t)bh * DH + vdh) * S;
  const int sfix = (ql & 7) << 3;

  for (int half = 0; half < 2; half++) {
    const int strip = half ? 7 - pr : pr;
    const int qw0 = strip * 256 + w * 32;

    bf16x8 qf[8];
    const unsigned short* qp = Q + base + (size_t)(qw0 + ql) * DH + hi * 8;
#pragma unroll
    for (int t = 0; t < 8; t++) qf[t] = *(const bf16x8*)(qp + t * 16);

    f32x16 acc[4];
#pragma unroll
    for (int mt = 0; mt < 4; mt++) acc[mt] = (f32x16)0.f;
    float m = -INFINITY, lsum = 0.f;

    const int ntb = 8 * (strip + 1);
    const int last = 8 * strip + w;

    {
      f32x4 kr = *(const f32x4*)(Kgb + tid * 8);
      f32x4 vr = *(const f32x4*)(Vgr + vc);
      *(f32x4*)(&lK[0][kdst]) = kr;
      *(f32x4*)(&lV[0][vdst]) = vr;
      __syncthreads();
    }

    for (int kb = 0; kb < ntb; kb++) {
      const int cur = kb & 1;
      const bool more = (kb + 1 < ntb);
      f32x4 kr, vr;
      if (more) {
        kr = *(const f32x4*)(Kgb + (size_t)(kb + 1) * 4096 + tid * 8);
        vr = *(const f32x4*)(Vgr + (kb + 1) * 32 + vc);
      }
      if (kb <= last) {
        const unsigned short* kbuf = lK[cur];
        const unsigned short* vbuf = lV[cur];
        f32x16 st0 = (f32x16)0.f, st1 = (f32x16)0.f;
#pragma unroll
        for (int t = 0; t < 4; t++) {
          bf16x8 k0 = *(const bf16x8*)(kbuf + ((ql * 128 + (2 * t) * 16 + 8 * hi) ^ sfix));
          bf16x8 k1 = *(const bf16x8*)(kbuf + ((ql * 128 + (2 * t + 1) * 16 + 8 * hi) ^ sfix));
          st0 = __builtin_amdgcn_mfma_f32_32x32x16_bf16(k0, qf[2 * t], st0, 0, 0, 0);
          st1 = __builtin_amdgcn_mfma_f32_32x32x16_bf16(k1, qf[2 * t + 1], st1, 0, 0, 0);
        }
        float sv[16];
#pragma unroll
        for (int r = 0; r < 16; r++) sv[r] = st0[r] + st1[r];
        if (kb == last) {
#pragma unroll
          for (int r = 0; r < 16; r++) {
            const int klocal = (r & 3) + 8 * (r >> 2) + 4 * hi;
            sv[r] = (klocal > ql) ? -INFINITY : sv[r];
          }
        }
        float smax = sv[0];
#pragma unroll
        for (int r = 1; r < 16; r++) smax = fmaxf(smax, sv[r]);
        smax = fmaxf(smax, __shfl_xor(smax, 32));

        float fr = 1.f;
        if (!__all((smax - m) * cl <= 8.0f)) {
          const float mn = fmaxf(m, smax);
          fr = exp2f((m - mn) * cl);
          m = mn;
#pragma unroll
          for (int mt = 0; mt < 4; mt++)
#pragma unroll
            for (int r = 0; r < 16; r++) acc[mt][r] *= fr;
        }
        float p[16];
        float ps = 0.f;
#pragma unroll
        for (int r = 0; r < 16; r++) {
          p[r] = exp2f((sv[r] - m) * cl);
          ps += p[r];
        }
        lsum = lsum * fr + ps + __shfl_xor(ps, 32);

        unsigned W[8];
#pragma unroll
        for (int qd = 0; qd < 4; qd++) {
          W[2 * qd]     = (unsigned)f2bf(p[4 * qd])     | ((unsigned)f2bf(p[4 * qd + 1]) << 16);
          W[2 * qd + 1] = (unsigned)f2bf(p[4 * qd + 2]) | ((unsigned)f2bf(p[4 * qd + 3]) << 16);
        }
#pragma unroll
        for (int t = 0; t < 2; t++) {
          const unsigned s0 = hi ? W[4 * t] : W[4 * t + 2];
          const unsigned s1 = hi ? W[4 * t + 1] : W[4 * t + 3];
          const unsigned r0 = __shfl_xor((int)s0, 32);
          const unsigned r1 = __shfl_xor((int)s1, 32);
          union { unsigned u[4]; bf16x8 v; } pf;
          if (hi == 0) { pf.u[0] = W[4 * t]; pf.u[1] = W[4 * t + 1]; pf.u[2] = r0; pf.u[3] = r1; }
          else         { pf.u[0] = r0; pf.u[1] = r1; pf.u[2] = W[4 * t + 2]; pf.u[3] = W[4 * t + 3]; }
#pragma unroll
          for (int mt = 0; mt < 4; mt++) {
            const bf16x8 vf = *(const bf16x8*)(vbuf + (mt * 32 + ql) * 40 + 16 * t + 8 * hi);
            acc[mt] = __builtin_amdgcn_mfma_f32_32x32x16_bf16(vf, pf.v, acc[mt], 0, 0, 0);
          }
        }
      }
      if (more) {
        *(f32x4*)(&lK[cur ^ 1][kdst]) = kr;
        *(f32x4*)(&lV[cur ^ 1][vdst]) = vr;
      }
      __syncthreads();
    }

    const float inv = 1.f / lsum;
    const int s_glob = qw0 + ql;
    unsigned short* op = O + ((size_t)(b * S + s_glob) * H + h) * DH;
#pragma unroll
    for (int mt = 0; mt < 4; mt++)
#pragma unroll
      for (int g = 0; g < 4; g++) {
        u16x4 ov;
#pragma unroll
        for (int jj = 0; jj < 4; jj++) ov[jj] = f2bf(acc[mt][4 * g + jj] * inv);
        *(u16x4*)(op + mt * 32 + 8 * g + 4 * hi) = ov;
      }
  }
}

extern "C" void kernel_launch(void* const* d_in, const int* in_sizes, int n_in,
                              void* d_out, int out_size, void* d_ws, size_t ws_size,
                              hipStream_t stream) {
  const float* x    = (const float*)d_in[0];
  const float* cosT = (const float*)d_in[1];
  const float* sinT = (const float*)d_in[2];
  const float* Wqkv = (const float*)d_in[3];
  const float* bqkv = (const float*)d_in[4];
  const float* Wout = (const float*)d_in[5];
  const float* bout = (const float*)d_in[6];

  char* ws = (char*)d_ws;
  unsigned short* xbf   = (unsigned short*)(ws);
  unsigned short* WqkvT = (unsigned short*)(ws + ((size_t)32 << 20));
  unsigned short* WoutT = (unsigned short*)(ws + ((size_t)56 << 20));
  unsigned short* VTb   = (unsigned short*)(ws + ((size_t)64 << 20));
  unsigned short* Qb = (unsigned short*)d_out;
  unsigned short* Kb = (unsigned short*)d_out + (size_t)M * D;
  unsigned short* Ob = xbf;

  cvt_kernel<<<M * D / 1024, 256, 0, stream>>>(x, xbf);
  transpose_kernel<<<dim3(N3 / 32, D / 32), dim3(32, 8), 0, stream>>>(Wqkv, WqkvT, D, N3);
  transpose_kernel<<<dim3(D / 32, D / 32), dim3(32, 8), 0, stream>>>(Wout, WoutT, D, D);
  gemm_bt<0><<<dim3((M / 256) * (N3 / 256)), 512, 0, stream>>>(xbf, WqkvT, bqkv, nullptr,
                                                               Qb, Kb, VTb, N3, N3 / 256);
  rope_kernel<<<(B * H * S * 16) / 256, 256, 0, stream>>>(Qb, cosT, sinT);
  rope_kernel<<<(B * H * S * 16) / 256, 256, 0, stream>>>(Kb, cosT, sinT);
  attn3_kernel<<<B * H * 4, 512, 0, stream>>>(Qb, Kb, VTb, Ob);
  gemm_bt<1><<<dim3((M / 256) * (D / 256)), 512, 0, stream>>>(Ob, WoutT, bout, (float*)d_out,
                                                              nullptr, nullptr, nullptr, D, D / 256);
}